// Round 10
// baseline (136.434 us; speedup 1.0000x reference)
//
#include <hip/hip_runtime.h>
#include <math.h>

#define B_SZ 2
#define S_SZ 2048
#define E_SZ 1024
#define H_SZ 16
#define HD_SZ 64

// (1/sqrt(HD)) * log2(e) -- fold softmax scale and exp->exp2 into Q
#define ATT_SCALE 0.1803368801111306f
// log2(10000)/16
#define ROPE_L2 0.8304820237218407f

typedef unsigned short u16;
typedef unsigned int u32;
typedef __bf16 bf16_t;
typedef bf16_t bf16x8 __attribute__((ext_vector_type(8)));
typedef float f32x4 __attribute__((ext_vector_type(4)));

__device__ __forceinline__ u16 f2bf(float f) {
    bf16_t h = (bf16_t)f;                 // HW RTNE convert
    union { bf16_t h; u16 u; } v; v.h = h;
    return v.u;
}

__device__ __forceinline__ void gload_lds16(const void* g, void* l) {
    __builtin_amdgcn_global_load_lds(
        (const __attribute__((address_space(1))) unsigned int*)g,
        (__attribute__((address_space(3))) unsigned int*)l, 16, 0, 0);
}

// ---------------------------------------------------------------------------
// init: RoPE cos/sin table (blocks 0..127) + fp32->bf16 casts (blocks 128..)
// ---------------------------------------------------------------------------
#define N_X   4194304L
#define N_QA  524288L
#define N_QB  524288L
#define N_KVA 557056L
#define N_KVB 786432L

__global__ __launch_bounds__(256) void init_kernel(
    const float* __restrict__ x, const float* __restrict__ wqa,
    const float* __restrict__ wqb, const float* __restrict__ wkva,
    const float* __restrict__ wkvb, const float* __restrict__ wout,
    u16* __restrict__ xb, u16* __restrict__ wqab, u16* __restrict__ wqbb,
    u16* __restrict__ wkvab, u16* __restrict__ wkvbb, u16* __restrict__ woutb,
    float2* __restrict__ tbl)
{
    if (blockIdx.x < 128) {
        const int idx = blockIdx.x * 256 + threadIdx.x;   // 32768
        const int s = idx >> 4, i = idx & 15;
        const float invf = exp2f(-(float)i * ROPE_L2);
        float sn, c;
        sincosf((float)s * invf, &sn, &c);
        tbl[idx] = make_float2(c, sn);
        return;
    }
    long i = ((long)(blockIdx.x - 128) * 256 + threadIdx.x) * 8;
    const long c0 = N_X, c1 = c0 + N_QA, c2 = c1 + N_QB, c3 = c2 + N_KVA, c4 = c3 + N_KVB;
    const float* src; u16* dst; long off;
    if      (i < c0) { src = x;    dst = xb;    off = i; }
    else if (i < c1) { src = wqa;  dst = wqab;  off = i - c0; }
    else if (i < c2) { src = wqb;  dst = wqbb;  off = i - c1; }
    else if (i < c3) { src = wkva; dst = wkvab; off = i - c2; }
    else if (i < c4) { src = wkvb; dst = wkvbb; off = i - c3; }
    else             { src = wout; dst = woutb; off = i - c4; }
    float v[8];
    *(float4*)v       = *(const float4*)(src + off);
    *(float4*)(v + 4) = *(const float4*)(src + off + 4);
    u32 o[4];
    #pragma unroll
    for (int k = 0; k < 4; ++k)
        o[k] = (u32)f2bf(v[2*k]) | ((u32)f2bf(v[2*k+1]) << 16);
    *(uint4*)(dst + off) = *(const uint4*)o;
}

// ---------------------------------------------------------------------------
// bf16 NT GEMM body: C[M,N] = A[M,K] * B[N,K]^T, fp32 accumulate.
// 128x128 tile, BK=32, 4 waves. global_load_lds + chunk-XOR swizzle.
// ---------------------------------------------------------------------------
template<bool BF16OUT>
__device__ __forceinline__ void gemm_body(
    const u16* __restrict__ A, int lda,
    const u16* __restrict__ Bm, int ldb,
    void* __restrict__ Cout, int ldc, int N, int K,
    int m0, int n0, u16* smA, u16* smB)
{
    const int tid = threadIdx.x;
    const int wave = tid >> 6, lane = tid & 63;
    const int wm = wave >> 1, wn = wave & 1;

    f32x4 acc[4][4] = {};
    const int rA0 = wm * 64 + (lane & 15);
    const int rB0 = wn * 64 + (lane & 15);
    const int cfr = lane >> 4;

    for (int k0 = 0; k0 < K; k0 += 32) {
        #pragma unroll
        for (int j = 0; j < 2; ++j) {
            const int boff = j * 4096 + wave * 1024;
            const int r  = (boff >> 6) + (lane >> 2);
            const int ch = lane & 3;
            const int sw = (ch ^ ((r >> 1) & 3)) * 8;
            gload_lds16(A + (size_t)(m0 + r) * lda + k0 + sw, (char*)smA + boff);
            const int nr = min(n0 + r, N - 1);
            gload_lds16(Bm + (size_t)nr * ldb + k0 + sw, (char*)smB + boff);
        }
        __syncthreads();
        bf16x8 af[4], bfr[4];
        #pragma unroll
        for (int f = 0; f < 4; ++f) {
            const int rA = rA0 + f * 16;
            af[f]  = *(const bf16x8*)(smA + rA * 32 + ((cfr ^ ((rA >> 1) & 3)) * 8));
            const int rB = rB0 + f * 16;
            bfr[f] = *(const bf16x8*)(smB + rB * 32 + ((cfr ^ ((rB >> 1) & 3)) * 8));
        }
        #pragma unroll
        for (int i = 0; i < 4; ++i)
            #pragma unroll
            for (int j = 0; j < 4; ++j)
                acc[i][j] = __builtin_amdgcn_mfma_f32_16x16x32_bf16(af[i], bfr[j], acc[i][j], 0, 0, 0);
        __syncthreads();
    }

    const int cn = lane & 15, rq = lane >> 4;
    #pragma unroll
    for (int i = 0; i < 4; ++i) {
        #pragma unroll
        for (int j = 0; j < 4; ++j) {
            const int n = n0 + wn * 64 + j * 16 + cn;
            if (n < N) {
                #pragma unroll
                for (int r = 0; r < 4; ++r) {
                    const size_t row = (size_t)(m0 + wm * 64 + i * 16 + rq * 4 + r);
                    if (BF16OUT) ((u16*)Cout)[row * ldc + n] = f2bf(acc[i][j][r]);
                    else         ((float*)Cout)[row * ldc + n] = acc[i][j][r];
                }
            }
        }
    }
}

// XCD-chunked block swizzle: keep ~nblk/8 consecutive work items per XCD.
__device__ __forceinline__ int swz_bid() {
    const int nx = gridDim.x;
    const int bid = blockIdx.x + nx * blockIdx.y;
    const int cpx = (nx * gridDim.y) >> 3;     // grid total must be %8==0
    return (bid & 7) * cpx + (bid >> 3);
}

template<bool BF16OUT>
__global__ __launch_bounds__(256) void gemm_bt_bf16(
    const u16* __restrict__ A, int lda,
    const u16* __restrict__ Bm, int ldb,
    void* __restrict__ Cout, int ldc, int N, int K)
{
    __shared__ u16 smA[128 * 32];
    __shared__ u16 smB[128 * 32];
    const int w = swz_bid();
    const int nx = gridDim.x;
    gemm_body<BF16OUT>(A, lda, Bm, ldb, Cout, ldc, N, K,
                       (w / nx) * 128, (w % nx) * 128, smA, smB);
}

// fused gemm1+gemm4: both read A=xb (K=1024). bx<4 -> qc (N=512, fp32),
// else kva (N=544, fp32).
__global__ __launch_bounds__(256) void gemm_dual(
    const u16* __restrict__ A,
    const u16* __restrict__ B1, float* __restrict__ C1,
    const u16* __restrict__ B2, float* __restrict__ C2)
{
    __shared__ u16 smA[128 * 32];
    __shared__ u16 smB[128 * 32];
    const int w = swz_bid();
    const int bx = w % 9, by = w / 9;
    if (bx < 4)
        gemm_body<false>(A, 1024, B1, 1024, C1, 512, 512, 1024,
                         by * 128, bx * 128, smA, smB);
    else
        gemm_body<false>(A, 1024, B2, 1024, C2, 544, 544, 1024,
                         by * 128, (bx - 4) * 128, smA, smB);
}

// ---------------------------------------------------------------------------
// fused LayerNorms (fp32 in): blocks [0,4096) -> LN(qc)->qcb;
// [4096,8192) -> LN(kva)->ckvb + RoPE(kva[:,512:544])->kpe (fp32).
// ---------------------------------------------------------------------------
__global__ __launch_bounds__(256) void ln2_kernel(
    const float* __restrict__ qc, const float* __restrict__ kva,
    const float* __restrict__ g_qa, const float* __restrict__ b_qa,
    const float* __restrict__ g_kva, const float* __restrict__ b_kva,
    u16* __restrict__ qcb, u16* __restrict__ ckvb,
    float* __restrict__ kpe, const float2* __restrict__ tbl)
{
    const bool qpart = blockIdx.x < 4096;
    const int row = blockIdx.x & 4095;
    const float* in    = qpart ? qc : kva;
    const int ld       = qpart ? 512 : 544;
    const float* gamma = qpart ? g_qa : g_kva;
    const float* beta  = qpart ? b_qa : b_kva;
    u16* outb          = qpart ? qcb : ckvb;

    const float* p = in + (size_t)row * ld;
    const int t = threadIdx.x;
    float v0 = p[t], v1 = p[t + 256];

    __shared__ float red[4];
    const int wave = t >> 6, lane = t & 63;

    float s = v0 + v1;
    #pragma unroll
    for (int o = 1; o < 64; o <<= 1) s += __shfl_xor(s, o);
    if (lane == 0) red[wave] = s;
    __syncthreads();
    const float mu = (red[0] + red[1] + red[2] + red[3]) * (1.f / 512.f);

    const float d0 = v0 - mu, d1 = v1 - mu;
    float s2 = d0 * d0 + d1 * d1;
    #pragma unroll
    for (int o = 1; o < 64; o <<= 1) s2 += __shfl_xor(s2, o);
    __syncthreads();
    if (lane == 0) red[wave] = s2;
    __syncthreads();
    const float var = (red[0] + red[1] + red[2] + red[3]) * (1.f / 512.f);
    const float rs = rsqrtf(var + 1e-5f);

    outb[(size_t)row * 512 + t]       = f2bf(d0 * rs * gamma[t]       + beta[t]);
    outb[(size_t)row * 512 + t + 256] = f2bf(d1 * rs * gamma[t + 256] + beta[t + 256]);

    if (!qpart && t < 16) {
        const int spos = row & (S_SZ - 1);
        const float2 cs = tbl[spos * 16 + t];
        const float x1 = p[512 + 2*t], x2 = p[512 + 2*t + 1];
        kpe[(size_t)row * 32 + 2*t]     = x1 * cs.x - x2 * cs.y;
        kpe[(size_t)row * 32 + 2*t + 1] = x1 * cs.y + x2 * cs.x;
    }
}

// ---------------------------------------------------------------------------
// fused q-GEMM + kv-GEMM + k_pe broadcast (grid 21 x 32):
//  bx<8  : q = qcb @ Wqb^T; epilogue fuses RoPE + ATT_SCALE + swizzled pack
//          directly into qpack (B*H, S, 64)
//  bx<20 : kv = ckvb @ Wkvb^T; epilogue scatters k_nope into kpack and
//          v (transposed, pi-permuted, swizzled) into vt -- no kvd buffer
//  bx==20: broadcast roped k_pe (fp32 kpe) into kpack for all 16 heads
//          (128 rows x 4 chunks per block: row = by*128+rr*64+(tid>>2),
//           p = 4+(tid&3) covers ALL 32 k_pe dims -- R9 bug fixed)
// ---------------------------------------------------------------------------
__global__ __launch_bounds__(256) void gemm_qkv(
    const u16* __restrict__ qcb, const u16* __restrict__ wqbb,
    const u16* __restrict__ ckvb, const u16* __restrict__ wkvbb,
    const float* __restrict__ kpe, const float2* __restrict__ tbl,
    u16* __restrict__ qpack, u16* __restrict__ kpack, u16* __restrict__ vt)
{
    __shared__ u16 smA[128 * 32];
    __shared__ u16 smB[128 * 32];
    const int tid = threadIdx.x;
    const int wsw = swz_bid();
    const int bx = wsw % 21, by = wsw / 21;

    if (bx == 20) {
        // k_pe broadcast: 128 rows x chunks p=4..7, 16 head copies each
        #pragma unroll
        for (int rr = 0; rr < 2; ++rr) {
            const int row = by * 128 + rr * 64 + (tid >> 2);
            const int p = 4 + (tid & 3);
            const int s = row & (S_SZ - 1), b = row >> 11;
            const float* src = kpe + (size_t)row * 32 + (p - 4) * 8;
            float v[8];
            *(float4*)v       = *(const float4*)(src);
            *(float4*)(v + 4) = *(const float4*)(src + 4);
            u32 o[4];
            #pragma unroll
            for (int k = 0; k < 4; ++k)
                o[k] = (u32)f2bf(v[2*k]) | ((u32)f2bf(v[2*k+1]) << 16);
            const int sch = p ^ (s & 7);
            #pragma unroll
            for (int h = 0; h < 16; ++h)
                *(uint4*)(kpack + (((size_t)(b * 16 + h) * S_SZ + s) * 64) + sch * 8) = *(const uint4*)o;
        }
        return;
    }

    const int wave = tid >> 6, lane = tid & 63;
    const int wm = wave >> 1, wn = wave & 1;
    const bool qpath = bx < 8;
    const u16* A  = qpath ? qcb : ckvb;
    const u16* Bm = qpath ? wqbb : wkvbb;
    const int n0 = (qpath ? bx : bx - 8) * 128;
    const int m0 = by * 128;

    f32x4 acc[4][4] = {};
    const int rA0 = wm * 64 + (lane & 15);
    const int rB0 = wn * 64 + (lane & 15);
    const int cfr = lane >> 4;

    for (int k0 = 0; k0 < 512; k0 += 32) {
        #pragma unroll
        for (int j = 0; j < 2; ++j) {
            const int boff = j * 4096 + wave * 1024;
            const int r  = (boff >> 6) + (lane >> 2);
            const int ch = lane & 3;
            const int sw = (ch ^ ((r >> 1) & 3)) * 8;
            gload_lds16(A + (size_t)(m0 + r) * 512 + k0 + sw, (char*)smA + boff);
            gload_lds16(Bm + (size_t)(n0 + r) * 512 + k0 + sw, (char*)smB + boff);
        }
        __syncthreads();
        bf16x8 af[4], bfr[4];
        #pragma unroll
        for (int f = 0; f < 4; ++f) {
            const int rA = rA0 + f * 16;
            af[f]  = *(const bf16x8*)(smA + rA * 32 + ((cfr ^ ((rA >> 1) & 3)) * 8));
            const int rB = rB0 + f * 16;
            bfr[f] = *(const bf16x8*)(smB + rB * 32 + ((cfr ^ ((rB >> 1) & 3)) * 8));
        }
        #pragma unroll
        for (int i = 0; i < 4; ++i)
            #pragma unroll
            for (int j = 0; j < 4; ++j)
                acc[i][j] = __builtin_amdgcn_mfma_f32_16x16x32_bf16(af[i], bfr[j], acc[i][j], 0, 0, 0);
        __syncthreads();
    }

    const int cn = lane & 15, rq = lane >> 4;
    if (qpath) {
        #pragma unroll
        for (int i = 0; i < 4; ++i) {
            #pragma unroll
            for (int j = 0; j < 4; ++j) {
                const int n = n0 + wn * 64 + j * 16 + cn;
                const int d = n & 63, h = n >> 6;
                #pragma unroll
                for (int r = 0; r < 4; ++r) {
                    const int row = m0 + wm * 64 + i * 16 + rq * 4 + r;
                    const int s = row & (S_SZ - 1), b = row >> 11;
                    const float val = acc[i][j][r];
                    const float prt = __shfl_xor(val, 1);   // RoPE pair partner
                    float o;
                    if (d >= 32) {
                        const float2 cs = tbl[s * 16 + ((d - 32) >> 1)];
                        o = (d & 1) ? (prt * cs.y + val * cs.x)
                                    : (val * cs.x - prt * cs.y);
                    } else {
                        o = val;
                    }
                    o *= ATT_SCALE;
                    const int sch = (d >> 3) ^ (s & 7);
                    qpack[(((size_t)(b * 16 + h) * S_SZ + s) * 64) + sch * 8 + (d & 7)] = f2bf(o);
                }
            }
        }
    } else {
        // scatter directly into kpack (k_nope) / vt (transposed + pi + swizzle)
        #pragma unroll
        for (int j = 0; j < 4; ++j) {
            const int n = n0 + wn * 64 + j * 16 + cn;   // 0..1535
            const int h = n / 96;
            const int dd = n - h * 96;
            const bool isk = dd < 32;
            const int d = dd - 32;
            #pragma unroll
            for (int i = 0; i < 4; ++i) {
                #pragma unroll
                for (int r = 0; r < 4; ++r) {
                    const int row = m0 + wm * 64 + i * 16 + rq * 4 + r;
                    const int s = row & (S_SZ - 1), b = row >> 11;
                    const u16 val = f2bf(acc[i][j][r]);
                    if (isk) {
                        kpack[(((size_t)(b * 16 + h) * S_SZ + s) * 64)
                              + (((dd >> 3) ^ (s & 7)) * 8) + (dd & 7)] = val;
                    } else {
                        const int kk = s & 63, kt = s >> 6;
                        // jj = pi_v^{-1}(kk): slot whose permuted key is kk
                        const int jj = (kk & 32) | ((kk & 8) << 1) | ((kk & 4) << 1)
                                     | ((kk & 16) >> 2) | (kk & 3);
                        vt[(((size_t)(b * 16 + h) * 32 + kt) * 64 + d) * 64
                           + (((jj >> 3) ^ (d & 7)) * 8) + (jj & 7)] = val;
                    }
                }
            }
        }
    }
}

// ---------------------------------------------------------------------------
// MFMA flash attention, swapped-operand, QBLK=128, no max tracking,
// SPLIT-K in-block: 8 waves; waves 0-3 keys [0,1024), waves 4-7 [1024,2048),
// each half double-buffered in its own 32KB LDS region. Partials additive;
// half-1 dumps acc/l to LDS once, half-0 combines and stores.
// ---------------------------------------------------------------------------
__global__ __launch_bounds__(512, 4) void attn_mfma_kernel(
    const u16* __restrict__ qpack, const u16* __restrict__ kpack,
    const u16* __restrict__ vt, u16* __restrict__ attout)
{
    __shared__ u16 KV[2][2][2][4096];   // [half][buf][K/V][tile] = 64 KB

    const int bid = blockIdx.x;                  // 0..511
    const int w0 = (bid & 7) * 64 + (bid >> 3);  // XCD-contiguous work id
    const int qt = w0 & 15, h = (w0 >> 4) & 15, b = w0 >> 8;
    const int bh = b * H_SZ + h;
    const int tid = threadIdx.x, wave = tid >> 6, lane = tid & 63;
    const int kw = wave >> 2, wv = wave & 3;     // K-half, wave-within-half
    const int g = lane >> 4, q15 = lane & 15;

    const u16* kbase = kpack + (size_t)bh * S_SZ * 64 + (size_t)(kw * 16) * 4096;
    const u16* vbase = vt + (size_t)bh * (S_SZ / 64) * 4096 + (size_t)(kw * 16) * 4096;

    // Q fragments straight from global (pre-swizzled)
    bf16x8 qa[2][2];
    {
        const u16* qbase = qpack + ((size_t)bh * S_SZ + qt * 128) * 64;
        #pragma unroll
        for (int qb = 0; qb < 2; ++qb) {
            const int r = wv * 32 + qb * 16 + q15;
            #pragma unroll
            for (int dh = 0; dh < 2; ++dh) {
                const int ch = dh * 4 + g;
                qa[qb][dh] = *(const bf16x8*)(qbase + r * 64 + ((ch ^ (r & 7)) * 8));
            }
        }
    }

    // loop-invariant LDS fragment byte offsets (relative to [half][buf] base)
    int koff[4][2], voff[2][4];
    #pragma unroll
    for (int fk = 0; fk < 4; ++fk) {
        const int kc = fk * 16 + q15;
        #pragma unroll
        for (int dh = 0; dh < 2; ++dh)
            koff[fk][dh] = kc * 128 + (((dh * 4 + g) ^ (kc & 7)) * 16);
    }
    #pragma unroll
    for (int kh = 0; kh < 2; ++kh)
        #pragma unroll
        for (int fd = 0; fd < 4; ++fd) {
            const int d = fd * 16 + q15;
            voff[kh][fd] = 8192 + d * 128 + (((kh * 4 + g) ^ (d & 7)) * 16);
        }

    // stage first tile of this half
    #pragma unroll
    for (int j = 0; j < 2; ++j) {
        const int boff = j * 4096 + wv * 1024;
        gload_lds16(kbase + boff / 2 + lane * 8, (char*)&KV[kw][0][0][0] + boff);
        gload_lds16(vbase + boff / 2 + lane * 8, (char*)&KV[kw][0][1][0] + boff);
    }
    __syncthreads();

    bf16x8 ones;
    #pragma unroll
    for (int e = 0; e < 8; ++e) ones[e] = (bf16_t)1.0f;

    f32x4 acc[2][4] = {};
    f32x4 acc_l[2] = {};

    #pragma unroll 2
    for (int t = 0; t < 16; ++t) {
        const char* base = (const char*)&KV[kw][t & 1][0][0];
        char* nbase = (char*)&KV[kw][(t + 1) & 1][0][0];

        // prefetch next tile of this half
        if (t != 15) {
            const u16* kn = kbase + (size_t)(t + 1) * 4096;
            const u16* vn = vbase + (size_t)(t + 1) * 4096;
            #pragma unroll
            for (int j = 0; j < 2; ++j) {
                const int boff = j * 4096 + wv * 1024;
                gload_lds16(kn + boff / 2 + lane * 8, nbase + boff);
                gload_lds16(vn + boff / 2 + lane * 8, nbase + 8192 + boff);
            }
        }

        // K fragments
        bf16x8 kb[4][2];
        #pragma unroll
        for (int fk = 0; fk < 4; ++fk)
            #pragma unroll
            for (int dh = 0; dh < 2; ++dh)
                kb[fk][dh] = *(const bf16x8*)(base + koff[fk][dh]);

        // QK^T (swapped): sc[qb][fk][r] = S[q15][key = fk*16 + 4g + r]
        f32x4 sc[2][4] = {};
        __builtin_amdgcn_s_setprio(1);
        #pragma unroll
        for (int qb = 0; qb < 2; ++qb)
            #pragma unroll
            for (int fk = 0; fk < 4; ++fk)
                #pragma unroll
                for (int dh = 0; dh < 2; ++dh)
                    sc[qb][fk] = __builtin_amdgcn_mfma_f32_16x16x32_bf16(kb[fk][dh], qa[qb][dh], sc[qb][fk], 0, 0, 0);
        __builtin_amdgcn_s_setprio(0);

        // P = exp2(sc) -- raw v_exp_f32
        #pragma unroll
        for (int qb = 0; qb < 2; ++qb)
            #pragma unroll
            for (int fk = 0; fk < 4; ++fk)
                #pragma unroll
                for (int r = 0; r < 4; ++r)
                    sc[qb][fk][r] = __builtin_amdgcn_exp2f(sc[qb][fk][r]);

        // pack P lane-locally: pa[qb][kh] supplies P[key-slot 8g+e][q]
        bf16x8 pa[2][2];
        #pragma unroll
        for (int qb = 0; qb < 2; ++qb)
            #pragma unroll
            for (int kh = 0; kh < 2; ++kh)
                #pragma unroll
                for (int e = 0; e < 4; ++e) {
                    pa[qb][kh][e]     = (bf16_t)sc[qb][2*kh][e];
                    pa[qb][kh][e + 4] = (bf16_t)sc[qb][2*kh + 1][e];
                }

        // V fragments + PV and l-sum MFMAs
        bf16x8 vb[2][4];
        #pragma unroll
        for (int kh = 0; kh < 2; ++kh)
            #pragma unroll
            for (int fd = 0; fd < 4; ++fd)
                vb[kh][fd] = *(const bf16x8*)(base + voff[kh][fd]);

        __builtin_amdgcn_s_setprio(1);
        #pragma unroll
        for (int kh = 0; kh < 2; ++kh)
            #pragma unroll
            for (int qb = 0; qb < 2; ++qb) {
                #pragma unroll
                for (int fd = 0; fd < 4; ++fd)
                    acc[qb][fd] = __builtin_amdgcn_mfma_f32_16x16x32_bf16(vb[kh][fd], pa[qb][kh], acc[qb][fd], 0, 0, 0);
                acc_l[qb] = __builtin_amdgcn_mfma_f32_16x16x32_bf16(ones, pa[qb][kh], acc_l[qb], 0, 0, 0);
            }
        __builtin_amdgcn_s_setprio(0);

        __syncthreads();
    }

    // combine halves through LDS (reuses KV; all loads drained by barriers).
    float* ex = (float*)&KV[0][0][0][0];
    const int slot = (wv * 64 + lane) * 36;
    if (kw == 1) {
        #pragma unroll
        for (int qb = 0; qb < 2; ++qb)
            #pragma unroll
            for (int fd = 0; fd < 4; ++fd)
                *(f32x4*)(ex + slot + (qb * 4 + fd) * 4) = acc[qb][fd];
        ex[slot + 32] = acc_l[0][0];
        ex[slot + 33] = acc_l[1][0];
    }
    __syncthreads();
    if (kw == 0) {
        #pragma unroll
        for (int qb = 0; qb < 2; ++qb) {
            const float l2 = acc_l[qb][0] + ex[slot + 32 + qb];
            const float inv = 1.0f / l2;
            const size_t row = (size_t)(b * S_SZ + qt * 128 + wv * 32 + qb * 16 + q15);
            #pragma unroll
            for (int fd = 0; fd < 4; ++fd) {
                const f32x4 o = acc[qb][fd] + *(const f32x4*)(ex + slot + (qb * 4 + fd) * 4);
                const int d0 = fd * 16 + 4 * g;
                u32 wlo = (u32)f2bf(o[0] * inv) | ((u32)f2bf(o[1] * inv) << 16);
                u32 whi = (u32)f2bf(o[2] * inv) | ((u32)f2bf(o[3] * inv) << 16);
                *(uint2*)(attout + row * 1024 + h * 64 + d0) = make_uint2(wlo, whi);
            }
        }
    }
}

// ---------------------------------------------------------------------------
extern "C" void kernel_launch(void* const* d_in, const int* in_sizes, int n_in,
                              void* d_out, int out_size, void* d_ws, size_t ws_size,
                              hipStream_t stream)
{
    (void)in_sizes; (void)n_in; (void)out_size; (void)ws_size;
    const float* x     = (const float*)d_in[0];
    const float* Wqa   = (const float*)d_in[1];
    const float* g_qa  = (const float*)d_in[2];
    const float* b_qa  = (const float*)d_in[3];
    const float* Wqb   = (const float*)d_in[4];
    const float* Wkva  = (const float*)d_in[5];
    const float* g_kva = (const float*)d_in[6];
    const float* b_kva = (const float*)d_in[7];
    const float* Wkvb  = (const float*)d_in[8];
    const float* Wout  = (const float*)d_in[9];
    float* out = (float*)d_out;

    // workspace (u16 units) with two safe aliases:
    //   qpack aliases xb  (xb dead after gemm_dual; qpack written by gemm_qkv)
    //   attout aliases qc (qc dead after ln2; attout written by attn)
    u16* p = (u16*)d_ws;
    u16* xb     = p;
    u16* qpack  = p;  p += 4194304;                 // 8 MB
    float* qc   = (float*)p;
    u16* attout = p;  p += 4194304;                 // 8 MB (2,097,152 f)
    float* kva  = (float*)p;  p += 4456448;         // 8.9 MB (2,228,224 f)
    u16* qcb    = p;  p += 2097152;                 // 4 MB
    u16* ckvb   = p;  p += 2097152;                 // 4 MB
    u16* kpack  = p;  p += 4194304;                 // 8 MB
    u16* vt     = p;  p += 4194304;                 // 8 MB
    float* kpe  = (float*)p;  p += 262144;          // 512 KB (131,072 f)
    float2* tbl = (float2*)p; p += 131072;          // 256 KB (32,768 float2)
    u16* wqab   = p;  p += 524288;
    u16* wqbb   = p;  p += 524288;
    u16* wkvab  = p;  p += 557056;
    u16* wkvbb  = p;  p += 786432;
    u16* woutb  = p;  p += 1048576;

    dim3 blk(256);

    // 1. RoPE table + bf16 casts (one launch)
    init_kernel<<<3856, blk, 0, stream>>>(x, Wqa, Wqb, Wkva, Wkvb, Wout,
                                          xb, wqab, wqbb, wkvab, wkvbb, woutb, tbl);
    // 2. qc = x @ Wqa^T (fp32) and kva = x @ Wkva^T (fp32)
    gemm_dual<<<dim3(9, 32), blk, 0, stream>>>(xb, wqab, qc, wkvab, kva);
    // 3. both LayerNorms (fp32 in, bf16 out + fp32 kpe)
    ln2_kernel<<<8192, blk, 0, stream>>>(qc, kva, g_qa, b_qa, g_kva, b_kva,
                                         qcb, ckvb, kpe, tbl);
    // 4. q-GEMM -> qpack, kv-GEMM -> kpack/vt direct, k_pe broadcast (fixed)
    gemm_qkv<<<dim3(21, 32), blk, 0, stream>>>(qcb, wqbb, ckvb, wkvbb, kpe, tbl,
                                               qpack, kpack, vt);
    // 5. flash attention (QBLK=128, split-K 8-wave, XCD-swizzled) -> attout
    attn_mfma_kernel<<<dim3(512), dim3(512), 0, stream>>>(qpack, kpack, vt, attout);
    // 6. out = attout @ Wout^T (fp32 -> d_out)
    gemm_bt_bf16<false><<<dim3(8, 32), blk, 0, stream>>>(attout, 1024, woutb, 1024, out, 1024, 1024, 1024);
}

// Round 11
// 130.837 us; speedup vs baseline: 1.0428x; 1.0428x over previous
//
#include <hip/hip_runtime.h>
#include <math.h>

#define B_SZ 2
#define S_SZ 2048
#define E_SZ 1024
#define H_SZ 16
#define HD_SZ 64

// (1/sqrt(HD)) * log2(e) -- fold softmax scale and exp->exp2 into Q
#define ATT_SCALE 0.1803368801111306f
// log2(10000)/16
#define ROPE_L2 0.8304820237218407f

typedef unsigned short u16;
typedef unsigned int u32;
typedef __bf16 bf16_t;
typedef bf16_t bf16x8 __attribute__((ext_vector_type(8)));
typedef float f32x4 __attribute__((ext_vector_type(4)));

__device__ __forceinline__ u16 f2bf(float f) {
    bf16_t h = (bf16_t)f;                 // HW RTNE convert
    union { bf16_t h; u16 u; } v; v.h = h;
    return v.u;
}

__device__ __forceinline__ void gload_lds16(const void* g, void* l) {
    __builtin_amdgcn_global_load_lds(
        (const __attribute__((address_space(1))) unsigned int*)g,
        (__attribute__((address_space(3))) unsigned int*)l, 16, 0, 0);
}

// ---------------------------------------------------------------------------
// init: RoPE cos/sin table (blocks 0..127) + fp32->bf16 casts (blocks 128..)
// ---------------------------------------------------------------------------
#define N_X   4194304L
#define N_QA  524288L
#define N_QB  524288L
#define N_KVA 557056L
#define N_KVB 786432L

__global__ __launch_bounds__(256) void init_kernel(
    const float* __restrict__ x, const float* __restrict__ wqa,
    const float* __restrict__ wqb, const float* __restrict__ wkva,
    const float* __restrict__ wkvb, const float* __restrict__ wout,
    u16* __restrict__ xb, u16* __restrict__ wqab, u16* __restrict__ wqbb,
    u16* __restrict__ wkvab, u16* __restrict__ wkvbb, u16* __restrict__ woutb,
    float2* __restrict__ tbl)
{
    if (blockIdx.x < 128) {
        const int idx = blockIdx.x * 256 + threadIdx.x;   // 32768
        const int s = idx >> 4, i = idx & 15;
        const float invf = exp2f(-(float)i * ROPE_L2);
        float sn, c;
        sincosf((float)s * invf, &sn, &c);
        tbl[idx] = make_float2(c, sn);
        return;
    }
    long i = ((long)(blockIdx.x - 128) * 256 + threadIdx.x) * 8;
    const long c0 = N_X, c1 = c0 + N_QA, c2 = c1 + N_QB, c3 = c2 + N_KVA, c4 = c3 + N_KVB;
    const float* src; u16* dst; long off;
    if      (i < c0) { src = x;    dst = xb;    off = i; }
    else if (i < c1) { src = wqa;  dst = wqab;  off = i - c0; }
    else if (i < c2) { src = wqb;  dst = wqbb;  off = i - c1; }
    else if (i < c3) { src = wkva; dst = wkvab; off = i - c2; }
    else if (i < c4) { src = wkvb; dst = wkvbb; off = i - c3; }
    else             { src = wout; dst = woutb; off = i - c4; }
    float v[8];
    *(float4*)v       = *(const float4*)(src + off);
    *(float4*)(v + 4) = *(const float4*)(src + off + 4);
    u32 o[4];
    #pragma unroll
    for (int k = 0; k < 4; ++k)
        o[k] = (u32)f2bf(v[2*k]) | ((u32)f2bf(v[2*k+1]) << 16);
    *(uint4*)(dst + off) = *(const uint4*)o;
}

// ---------------------------------------------------------------------------
// bf16 NT GEMM body, BK=64: C[M,N] = A[M,K] * B[N,K]^T, fp32 accumulate.
// 128x128 tile, 4 waves, single 32KB LDS buffer, ONE barrier pair per
// 64-wide K-step (half the barrier-drain of the BK=32 version).
// Rows are 64 u16 = 8 chunks of 16B; chunk-XOR swizzle key (r&7); staging
// pre-applies the inverse swizzle on the global source (XOR involution).
// Accumulation order identical to BK=32 (k ascending) -> bit-identical C.
// ---------------------------------------------------------------------------
template<bool BF16OUT>
__device__ __forceinline__ void gemm_body(
    const u16* __restrict__ A, int lda,
    const u16* __restrict__ Bm, int ldb,
    void* __restrict__ Cout, int ldc, int N, int K,
    int m0, int n0, u16* smA, u16* smB)
{
    const int tid = threadIdx.x;
    const int wave = tid >> 6, lane = tid & 63;
    const int wm = wave >> 1, wn = wave & 1;

    f32x4 acc[4][4] = {};
    const int rA0 = wm * 64 + (lane & 15);
    const int rB0 = wn * 64 + (lane & 15);
    const int cfr = lane >> 4;              // 0..3

    // staging slot: per issue j (0..3): row r = j*32 + wave*8 + (lane>>3),
    // slot = lane&7; source chunk = slot ^ (r&7) (inverse swizzle).
    const int srow = wave * 8 + (lane >> 3);
    const int slot = lane & 7;

    for (int k0 = 0; k0 < K; k0 += 64) {
        #pragma unroll
        for (int j = 0; j < 4; ++j) {
            const int r = j * 32 + srow;
            const int boff = j * 4096 + wave * 1024 + (lane << 4);   // bytes
            const int sw = (slot ^ (r & 7)) * 8;
            gload_lds16(A + (size_t)(m0 + r) * lda + k0 + sw, (char*)smA + boff);
            const int nr = min(n0 + r, N - 1);
            gload_lds16(Bm + (size_t)nr * ldb + k0 + sw, (char*)smB + boff);
        }
        __syncthreads();
        #pragma unroll
        for (int hk = 0; hk < 2; ++hk) {
            bf16x8 af[4], bfr[4];
            #pragma unroll
            for (int f = 0; f < 4; ++f) {
                const int rA = rA0 + f * 16;
                af[f]  = *(const bf16x8*)(smA + rA * 64 + (((hk * 4 + cfr) ^ (rA & 7)) * 8));
                const int rB = rB0 + f * 16;
                bfr[f] = *(const bf16x8*)(smB + rB * 64 + (((hk * 4 + cfr) ^ (rB & 7)) * 8));
            }
            #pragma unroll
            for (int i = 0; i < 4; ++i)
                #pragma unroll
                for (int j = 0; j < 4; ++j)
                    acc[i][j] = __builtin_amdgcn_mfma_f32_16x16x32_bf16(af[i], bfr[j], acc[i][j], 0, 0, 0);
        }
        __syncthreads();
    }

    const int cn = lane & 15, rq = lane >> 4;
    #pragma unroll
    for (int i = 0; i < 4; ++i) {
        #pragma unroll
        for (int j = 0; j < 4; ++j) {
            const int n = n0 + wn * 64 + j * 16 + cn;
            if (n < N) {
                #pragma unroll
                for (int r = 0; r < 4; ++r) {
                    const size_t row = (size_t)(m0 + wm * 64 + i * 16 + rq * 4 + r);
                    if (BF16OUT) ((u16*)Cout)[row * ldc + n] = f2bf(acc[i][j][r]);
                    else         ((float*)Cout)[row * ldc + n] = acc[i][j][r];
                }
            }
        }
    }
}

// XCD-chunked block swizzle: keep ~nblk/8 consecutive work items per XCD.
__device__ __forceinline__ int swz_bid() {
    const int nx = gridDim.x;
    const int bid = blockIdx.x + nx * blockIdx.y;
    const int cpx = (nx * gridDim.y) >> 3;     // grid total must be %8==0
    return (bid & 7) * cpx + (bid >> 3);
}

template<bool BF16OUT>
__global__ __launch_bounds__(256) void gemm_bt_bf16(
    const u16* __restrict__ A, int lda,
    const u16* __restrict__ Bm, int ldb,
    void* __restrict__ Cout, int ldc, int N, int K)
{
    __shared__ u16 smA[128 * 64];
    __shared__ u16 smB[128 * 64];
    const int w = swz_bid();
    const int nx = gridDim.x;
    gemm_body<BF16OUT>(A, lda, Bm, ldb, Cout, ldc, N, K,
                       (w / nx) * 128, (w % nx) * 128, smA, smB);
}

// fused gemm1+gemm4: both read A=xb (K=1024). bx<4 -> qc (N=512, fp32),
// else kva (N=544, fp32).
__global__ __launch_bounds__(256) void gemm_dual(
    const u16* __restrict__ A,
    const u16* __restrict__ B1, float* __restrict__ C1,
    const u16* __restrict__ B2, float* __restrict__ C2)
{
    __shared__ u16 smA[128 * 64];
    __shared__ u16 smB[128 * 64];
    const int w = swz_bid();
    const int bx = w % 9, by = w / 9;
    if (bx < 4)
        gemm_body<false>(A, 1024, B1, 1024, C1, 512, 512, 1024,
                         by * 128, bx * 128, smA, smB);
    else
        gemm_body<false>(A, 1024, B2, 1024, C2, 544, 544, 1024,
                         by * 128, (bx - 4) * 128, smA, smB);
}

// ---------------------------------------------------------------------------
// fused LayerNorms (fp32 in): blocks [0,4096) -> LN(qc)->qcb;
// [4096,8192) -> LN(kva)->ckvb + RoPE(kva[:,512:544])->kpe (fp32).
// ---------------------------------------------------------------------------
__global__ __launch_bounds__(256) void ln2_kernel(
    const float* __restrict__ qc, const float* __restrict__ kva,
    const float* __restrict__ g_qa, const float* __restrict__ b_qa,
    const float* __restrict__ g_kva, const float* __restrict__ b_kva,
    u16* __restrict__ qcb, u16* __restrict__ ckvb,
    float* __restrict__ kpe, const float2* __restrict__ tbl)
{
    const bool qpart = blockIdx.x < 4096;
    const int row = blockIdx.x & 4095;
    const float* in    = qpart ? qc : kva;
    const int ld       = qpart ? 512 : 544;
    const float* gamma = qpart ? g_qa : g_kva;
    const float* beta  = qpart ? b_qa : b_kva;
    u16* outb          = qpart ? qcb : ckvb;

    const float* p = in + (size_t)row * ld;
    const int t = threadIdx.x;
    float v0 = p[t], v1 = p[t + 256];

    __shared__ float red[4];
    const int wave = t >> 6, lane = t & 63;

    float s = v0 + v1;
    #pragma unroll
    for (int o = 1; o < 64; o <<= 1) s += __shfl_xor(s, o);
    if (lane == 0) red[wave] = s;
    __syncthreads();
    const float mu = (red[0] + red[1] + red[2] + red[3]) * (1.f / 512.f);

    const float d0 = v0 - mu, d1 = v1 - mu;
    float s2 = d0 * d0 + d1 * d1;
    #pragma unroll
    for (int o = 1; o < 64; o <<= 1) s2 += __shfl_xor(s2, o);
    __syncthreads();
    if (lane == 0) red[wave] = s2;
    __syncthreads();
    const float var = (red[0] + red[1] + red[2] + red[3]) * (1.f / 512.f);
    const float rs = rsqrtf(var + 1e-5f);

    outb[(size_t)row * 512 + t]       = f2bf(d0 * rs * gamma[t]       + beta[t]);
    outb[(size_t)row * 512 + t + 256] = f2bf(d1 * rs * gamma[t + 256] + beta[t + 256]);

    if (!qpart && t < 16) {
        const int spos = row & (S_SZ - 1);
        const float2 cs = tbl[spos * 16 + t];
        const float x1 = p[512 + 2*t], x2 = p[512 + 2*t + 1];
        kpe[(size_t)row * 32 + 2*t]     = x1 * cs.x - x2 * cs.y;
        kpe[(size_t)row * 32 + 2*t + 1] = x1 * cs.y + x2 * cs.x;
    }
}

// ---------------------------------------------------------------------------
// fused q-GEMM + kv-GEMM + k_pe broadcast (grid 21 x 32), BK=64 loop:
//  bx<8  : q = qcb @ Wqb^T; epilogue fuses RoPE + ATT_SCALE + swizzled pack
//          directly into qpack (B*H, S, 64)
//  bx<20 : kv = ckvb @ Wkvb^T; epilogue scatters k_nope into kpack and
//          v (transposed, pi-permuted, swizzled) into vt -- no kvd buffer
//  bx==20: broadcast roped k_pe (fp32 kpe) into kpack for all 16 heads
// ---------------------------------------------------------------------------
__global__ __launch_bounds__(256) void gemm_qkv(
    const u16* __restrict__ qcb, const u16* __restrict__ wqbb,
    const u16* __restrict__ ckvb, const u16* __restrict__ wkvbb,
    const float* __restrict__ kpe, const float2* __restrict__ tbl,
    u16* __restrict__ qpack, u16* __restrict__ kpack, u16* __restrict__ vt)
{
    __shared__ u16 smA[128 * 64];
    __shared__ u16 smB[128 * 64];
    const int tid = threadIdx.x;
    const int wsw = swz_bid();
    const int bx = wsw % 21, by = wsw / 21;

    if (bx == 20) {
        // k_pe broadcast: 128 rows x chunks p=4..7, 16 head copies each
        #pragma unroll
        for (int rr = 0; rr < 2; ++rr) {
            const int row = by * 128 + rr * 64 + (tid >> 2);
            const int p = 4 + (tid & 3);
            const int s = row & (S_SZ - 1), b = row >> 11;
            const float* src = kpe + (size_t)row * 32 + (p - 4) * 8;
            float v[8];
            *(float4*)v       = *(const float4*)(src);
            *(float4*)(v + 4) = *(const float4*)(src + 4);
            u32 o[4];
            #pragma unroll
            for (int k = 0; k < 4; ++k)
                o[k] = (u32)f2bf(v[2*k]) | ((u32)f2bf(v[2*k+1]) << 16);
            const int sch = p ^ (s & 7);
            #pragma unroll
            for (int h = 0; h < 16; ++h)
                *(uint4*)(kpack + (((size_t)(b * 16 + h) * S_SZ + s) * 64) + sch * 8) = *(const uint4*)o;
        }
        return;
    }

    const int wave = tid >> 6, lane = tid & 63;
    const int wm = wave >> 1, wn = wave & 1;
    const bool qpath = bx < 8;
    const u16* A  = qpath ? qcb : ckvb;
    const u16* Bm = qpath ? wqbb : wkvbb;
    const int n0 = (qpath ? bx : bx - 8) * 128;
    const int m0 = by * 128;

    f32x4 acc[4][4] = {};
    const int rA0 = wm * 64 + (lane & 15);
    const int rB0 = wn * 64 + (lane & 15);
    const int cfr = lane >> 4;
    const int srow = wave * 8 + (lane >> 3);
    const int slot = lane & 7;

    for (int k0 = 0; k0 < 512; k0 += 64) {
        #pragma unroll
        for (int j = 0; j < 4; ++j) {
            const int r = j * 32 + srow;
            const int boff = j * 4096 + wave * 1024 + (lane << 4);
            const int sw = (slot ^ (r & 7)) * 8;
            gload_lds16(A + (size_t)(m0 + r) * 512 + k0 + sw, (char*)smA + boff);
            gload_lds16(Bm + (size_t)(n0 + r) * 512 + k0 + sw, (char*)smB + boff);
        }
        __syncthreads();
        #pragma unroll
        for (int hk = 0; hk < 2; ++hk) {
            bf16x8 af[4], bfr[4];
            #pragma unroll
            for (int f = 0; f < 4; ++f) {
                const int rA = rA0 + f * 16;
                af[f]  = *(const bf16x8*)(smA + rA * 64 + (((hk * 4 + cfr) ^ (rA & 7)) * 8));
                const int rB = rB0 + f * 16;
                bfr[f] = *(const bf16x8*)(smB + rB * 64 + (((hk * 4 + cfr) ^ (rB & 7)) * 8));
            }
            #pragma unroll
            for (int i = 0; i < 4; ++i)
                #pragma unroll
                for (int j = 0; j < 4; ++j)
                    acc[i][j] = __builtin_amdgcn_mfma_f32_16x16x32_bf16(af[i], bfr[j], acc[i][j], 0, 0, 0);
        }
        __syncthreads();
    }

    const int cn = lane & 15, rq = lane >> 4;
    if (qpath) {
        #pragma unroll
        for (int i = 0; i < 4; ++i) {
            #pragma unroll
            for (int j = 0; j < 4; ++j) {
                const int n = n0 + wn * 64 + j * 16 + cn;
                const int d = n & 63, h = n >> 6;
                #pragma unroll
                for (int r = 0; r < 4; ++r) {
                    const int row = m0 + wm * 64 + i * 16 + rq * 4 + r;
                    const int s = row & (S_SZ - 1), b = row >> 11;
                    const float val = acc[i][j][r];
                    const float prt = __shfl_xor(val, 1);   // RoPE pair partner
                    float o;
                    if (d >= 32) {
                        const float2 cs = tbl[s * 16 + ((d - 32) >> 1)];
                        o = (d & 1) ? (prt * cs.y + val * cs.x)
                                    : (val * cs.x - prt * cs.y);
                    } else {
                        o = val;
                    }
                    o *= ATT_SCALE;
                    const int sch = (d >> 3) ^ (s & 7);
                    qpack[(((size_t)(b * 16 + h) * S_SZ + s) * 64) + sch * 8 + (d & 7)] = f2bf(o);
                }
            }
        }
    } else {
        // scatter directly into kpack (k_nope) / vt (transposed + pi + swizzle)
        #pragma unroll
        for (int j = 0; j < 4; ++j) {
            const int n = n0 + wn * 64 + j * 16 + cn;   // 0..1535
            const int h = n / 96;
            const int dd = n - h * 96;
            const bool isk = dd < 32;
            const int d = dd - 32;
            #pragma unroll
            for (int i = 0; i < 4; ++i) {
                #pragma unroll
                for (int r = 0; r < 4; ++r) {
                    const int row = m0 + wm * 64 + i * 16 + rq * 4 + r;
                    const int s = row & (S_SZ - 1), b = row >> 11;
                    const u16 val = f2bf(acc[i][j][r]);
                    if (isk) {
                        kpack[(((size_t)(b * 16 + h) * S_SZ + s) * 64)
                              + (((dd >> 3) ^ (s & 7)) * 8) + (dd & 7)] = val;
                    } else {
                        const int kk = s & 63, kt = s >> 6;
                        // jj = pi_v^{-1}(kk): slot whose permuted key is kk
                        const int jj = (kk & 32) | ((kk & 8) << 1) | ((kk & 4) << 1)
                                     | ((kk & 16) >> 2) | (kk & 3);
                        vt[(((size_t)(b * 16 + h) * 32 + kt) * 64 + d) * 64
                           + (((jj >> 3) ^ (d & 7)) * 8) + (jj & 7)] = val;
                    }
                }
            }
        }
    }
}

// ---------------------------------------------------------------------------
// MFMA flash attention, swapped-operand, QBLK=128, no max tracking,
// SPLIT-K in-block: 8 waves; waves 0-3 keys [0,1024), waves 4-7 [1024,2048),
// each half double-buffered in its own 32KB LDS region. Partials additive;
// half-1 dumps acc/l to LDS once, half-0 combines and stores.
// ---------------------------------------------------------------------------
__global__ __launch_bounds__(512, 4) void attn_mfma_kernel(
    const u16* __restrict__ qpack, const u16* __restrict__ kpack,
    const u16* __restrict__ vt, u16* __restrict__ attout)
{
    __shared__ u16 KV[2][2][2][4096];   // [half][buf][K/V][tile] = 64 KB

    const int bid = blockIdx.x;                  // 0..511
    const int w0 = (bid & 7) * 64 + (bid >> 3);  // XCD-contiguous work id
    const int qt = w0 & 15, h = (w0 >> 4) & 15, b = w0 >> 8;
    const int bh = b * H_SZ + h;
    const int tid = threadIdx.x, wave = tid >> 6, lane = tid & 63;
    const int kw = wave >> 2, wv = wave & 3;     // K-half, wave-within-half
    const int g = lane >> 4, q15 = lane & 15;

    const u16* kbase = kpack + (size_t)bh * S_SZ * 64 + (size_t)(kw * 16) * 4096;
    const u16* vbase = vt + (size_t)bh * (S_SZ / 64) * 4096 + (size_t)(kw * 16) * 4096;

    // Q fragments straight from global (pre-swizzled)
    bf16x8 qa[2][2];
    {
        const u16* qbase = qpack + ((size_t)bh * S_SZ + qt * 128) * 64;
        #pragma unroll
        for (int qb = 0; qb < 2; ++qb) {
            const int r = wv * 32 + qb * 16 + q15;
            #pragma unroll
            for (int dh = 0; dh < 2; ++dh) {
                const int ch = dh * 4 + g;
                qa[qb][dh] = *(const bf16x8*)(qbase + r * 64 + ((ch ^ (r & 7)) * 8));
            }
        }
    }

    // loop-invariant LDS fragment byte offsets (relative to [half][buf] base)
    int koff[4][2], voff[2][4];
    #pragma unroll
    for (int fk = 0; fk < 4; ++fk) {
        const int kc = fk * 16 + q15;
        #pragma unroll
        for (int dh = 0; dh < 2; ++dh)
            koff[fk][dh] = kc * 128 + (((dh * 4 + g) ^ (kc & 7)) * 16);
    }
    #pragma unroll
    for (int kh = 0; kh < 2; ++kh)
        #pragma unroll
        for (int fd = 0; fd < 4; ++fd) {
            const int d = fd * 16 + q15;
            voff[kh][fd] = 8192 + d * 128 + (((kh * 4 + g) ^ (d & 7)) * 16);
        }

    // stage first tile of this half
    #pragma unroll
    for (int j = 0; j < 2; ++j) {
        const int boff = j * 4096 + wv * 1024;
        gload_lds16(kbase + boff / 2 + lane * 8, (char*)&KV[kw][0][0][0] + boff);
        gload_lds16(vbase + boff / 2 + lane * 8, (char*)&KV[kw][0][1][0] + boff);
    }
    __syncthreads();

    bf16x8 ones;
    #pragma unroll
    for (int e = 0; e < 8; ++e) ones[e] = (bf16_t)1.0f;

    f32x4 acc[2][4] = {};
    f32x4 acc_l[2] = {};

    #pragma unroll 2
    for (int t = 0; t < 16; ++t) {
        const char* base = (const char*)&KV[kw][t & 1][0][0];
        char* nbase = (char*)&KV[kw][(t + 1) & 1][0][0];

        // prefetch next tile of this half
        if (t != 15) {
            const u16* kn = kbase + (size_t)(t + 1) * 4096;
            const u16* vn = vbase + (size_t)(t + 1) * 4096;
            #pragma unroll
            for (int j = 0; j < 2; ++j) {
                const int boff = j * 4096 + wv * 1024;
                gload_lds16(kn + boff / 2 + lane * 8, nbase + boff);
                gload_lds16(vn + boff / 2 + lane * 8, nbase + 8192 + boff);
            }
        }

        // K fragments
        bf16x8 kb[4][2];
        #pragma unroll
        for (int fk = 0; fk < 4; ++fk)
            #pragma unroll
            for (int dh = 0; dh < 2; ++dh)
                kb[fk][dh] = *(const bf16x8*)(base + koff[fk][dh]);

        // QK^T (swapped): sc[qb][fk][r] = S[q15][key = fk*16 + 4g + r]
        f32x4 sc[2][4] = {};
        __builtin_amdgcn_s_setprio(1);
        #pragma unroll
        for (int qb = 0; qb < 2; ++qb)
            #pragma unroll
            for (int fk = 0; fk < 4; ++fk)
                #pragma unroll
                for (int dh = 0; dh < 2; ++dh)
                    sc[qb][fk] = __builtin_amdgcn_mfma_f32_16x16x32_bf16(kb[fk][dh], qa[qb][dh], sc[qb][fk], 0, 0, 0);
        __builtin_amdgcn_s_setprio(0);

        // P = exp2(sc) -- raw v_exp_f32
        #pragma unroll
        for (int qb = 0; qb < 2; ++qb)
            #pragma unroll
            for (int fk = 0; fk < 4; ++fk)
                #pragma unroll
                for (int r = 0; r < 4; ++r)
                    sc[qb][fk][r] = __builtin_amdgcn_exp2f(sc[qb][fk][r]);

        // pack P lane-locally: pa[qb][kh] supplies P[key-slot 8g+e][q]
        bf16x8 pa[2][2];
        #pragma unroll
        for (int qb = 0; qb < 2; ++qb)
            #pragma unroll
            for (int kh = 0; kh < 2; ++kh)
                #pragma unroll
                for (int e = 0; e < 4; ++e) {
                    pa[qb][kh][e]     = (bf16_t)sc[qb][2*kh][e];
                    pa[qb][kh][e + 4] = (bf16_t)sc[qb][2*kh + 1][e];
                }

        // V fragments + PV and l-sum MFMAs
        bf16x8 vb[2][4];
        #pragma unroll
        for (int kh = 0; kh < 2; ++kh)
            #pragma unroll
            for (int fd = 0; fd < 4; ++fd)
                vb[kh][fd] = *(const bf16x8*)(base + voff[kh][fd]);

        __builtin_amdgcn_s_setprio(1);
        #pragma unroll
        for (int kh = 0; kh < 2; ++kh)
            #pragma unroll
            for (int qb = 0; qb < 2; ++qb) {
                #pragma unroll
                for (int fd = 0; fd < 4; ++fd)
                    acc[qb][fd] = __builtin_amdgcn_mfma_f32_16x16x32_bf16(vb[kh][fd], pa[qb][kh], acc[qb][fd], 0, 0, 0);
                acc_l[qb] = __builtin_amdgcn_mfma_f32_16x16x32_bf16(ones, pa[qb][kh], acc_l[qb], 0, 0, 0);
            }
        __builtin_amdgcn_s_setprio(0);

        __syncthreads();
    }

    // combine halves through LDS (reuses KV; all loads drained by barriers).
    float* ex = (float*)&KV[0][0][0][0];
    const int slot = (wv * 64 + lane) * 36;
    if (kw == 1) {
        #pragma unroll
        for (int qb = 0; qb < 2; ++qb)
            #pragma unroll
            for (int fd = 0; fd < 4; ++fd)
                *(f32x4*)(ex + slot + (qb * 4 + fd) * 4) = acc[qb][fd];
        ex[slot + 32] = acc_l[0][0];
        ex[slot + 33] = acc_l[1][0];
    }
    __syncthreads();
    if (kw == 0) {
        #pragma unroll
        for (int qb = 0; qb < 2; ++qb) {
            const float l2 = acc_l[qb][0] + ex[slot + 32 + qb];
            const float inv = 1.0f / l2;
            const size_t row = (size_t)(b * S_SZ + qt * 128 + wv * 32 + qb * 16 + q15);
            #pragma unroll
            for (int fd = 0; fd < 4; ++fd) {
                const f32x4 o = acc[qb][fd] + *(const f32x4*)(ex + slot + (qb * 4 + fd) * 4);
                const int d0 = fd * 16 + 4 * g;
                u32 wlo = (u32)f2bf(o[0] * inv) | ((u32)f2bf(o[1] * inv) << 16);
                u32 whi = (u32)f2bf(o[2] * inv) | ((u32)f2bf(o[3] * inv) << 16);
                *(uint2*)(attout + row * 1024 + h * 64 + d0) = make_uint2(wlo, whi);
            }
        }
    }
}

// ---------------------------------------------------------------------------
extern "C" void kernel_launch(void* const* d_in, const int* in_sizes, int n_in,
                              void* d_out, int out_size, void* d_ws, size_t ws_size,
                              hipStream_t stream)
{
    (void)in_sizes; (void)n_in; (void)out_size; (void)ws_size;
    const float* x     = (const float*)d_in[0];
    const float* Wqa   = (const float*)d_in[1];
    const float* g_qa  = (const float*)d_in[2];
    const float* b_qa  = (const float*)d_in[3];
    const float* Wqb   = (const float*)d_in[4];
    const float* Wkva  = (const float*)d_in[5];
    const float* g_kva = (const float*)d_in[6];
    const float* b_kva = (const float*)d_in[7];
    const float* Wkvb  = (const float*)d_in[8];
    const float* Wout  = (const float*)d_in[9];
    float* out = (float*)d_out;

    // workspace (u16 units) with two safe aliases:
    //   qpack aliases xb  (xb dead after gemm_dual; qpack written by gemm_qkv)
    //   attout aliases qc (qc dead after ln2; attout written by attn)
    u16* p = (u16*)d_ws;
    u16* xb     = p;
    u16* qpack  = p;  p += 4194304;                 // 8 MB
    float* qc   = (float*)p;
    u16* attout = p;  p += 4194304;                 // 8 MB (2,097,152 f)
    float* kva  = (float*)p;  p += 4456448;         // 8.9 MB (2,228,224 f)
    u16* qcb    = p;  p += 2097152;                 // 4 MB
    u16* ckvb   = p;  p += 2097152;                 // 4 MB
    u16* kpack  = p;  p += 4194304;                 // 8 MB
    u16* vt     = p;  p += 4194304;                 // 8 MB
    float* kpe  = (float*)p;  p += 262144;          // 512 KB (131,072 f)
    float2* tbl = (float2*)p; p += 131072;          // 256 KB (32,768 float2)
    u16* wqab   = p;  p += 524288;
    u16* wqbb   = p;  p += 524288;
    u16* wkvab  = p;  p += 557056;
    u16* wkvbb  = p;  p += 786432;
    u16* woutb  = p;  p += 1048576;

    dim3 blk(256);

    // 1. RoPE table + bf16 casts (one launch)
    init_kernel<<<3856, blk, 0, stream>>>(x, Wqa, Wqb, Wkva, Wkvb, Wout,
                                          xb, wqab, wqbb, wkvab, wkvbb, woutb, tbl);
    // 2. qc = x @ Wqa^T (fp32) and kva = x @ Wkva^T (fp32)  [BK=64]
    gemm_dual<<<dim3(9, 32), blk, 0, stream>>>(xb, wqab, qc, wkvab, kva);
    // 3. both LayerNorms (fp32 in, bf16 out + fp32 kpe)
    ln2_kernel<<<8192, blk, 0, stream>>>(qc, kva, g_qa, b_qa, g_kva, b_kva,
                                         qcb, ckvb, kpe, tbl);
    // 4. q-GEMM -> qpack, kv-GEMM -> kpack/vt direct, k_pe broadcast [BK=64]
    gemm_qkv<<<dim3(21, 32), blk, 0, stream>>>(qcb, wqbb, ckvb, wkvbb, kpe, tbl,
                                               qpack, kpack, vt);
    // 5. flash attention (QBLK=128, split-K 8-wave, XCD-swizzled) -> attout
    attn_mfma_kernel<<<dim3(512), dim3(512), 0, stream>>>(qpack, kpack, vt, attout);
    // 6. out = attout @ Wout^T (fp32 -> d_out)  [BK=64]
    gemm_bt_bf16<false><<<dim3(8, 32), blk, 0, stream>>>(attout, 1024, woutb, 1024, out, 1024, 1024, 1024);
}

// Round 12
// 129.825 us; speedup vs baseline: 1.0509x; 1.0078x over previous
//
#include <hip/hip_runtime.h>
#include <math.h>

#define B_SZ 2
#define S_SZ 2048
#define E_SZ 1024
#define H_SZ 16
#define HD_SZ 64

// (1/sqrt(HD)) * log2(e) -- fold softmax scale and exp->exp2 into Q
#define ATT_SCALE 0.1803368801111306f
// log2(10000)/16
#define ROPE_L2 0.8304820237218407f

typedef unsigned short u16;
typedef unsigned int u32;
typedef __bf16 bf16_t;
typedef bf16_t bf16x8 __attribute__((ext_vector_type(8)));
typedef float f32x4 __attribute__((ext_vector_type(4)));

__device__ __forceinline__ u16 f2bf(float f) {
    bf16_t h = (bf16_t)f;                 // HW RTNE convert
    union { bf16_t h; u16 u; } v; v.h = h;
    return v.u;
}

__device__ __forceinline__ void gload_lds16(const void* g, void* l) {
    __builtin_amdgcn_global_load_lds(
        (const __attribute__((address_space(1))) unsigned int*)g,
        (__attribute__((address_space(3))) unsigned int*)l, 16, 0, 0);
}

// ---------------------------------------------------------------------------
// init: RoPE cos/sin table (blocks 0..127) + fp32->bf16 casts (blocks 128..)
// ---------------------------------------------------------------------------
#define N_X   4194304L
#define N_QA  524288L
#define N_QB  524288L
#define N_KVA 557056L
#define N_KVB 786432L

__global__ __launch_bounds__(256) void init_kernel(
    const float* __restrict__ x, const float* __restrict__ wqa,
    const float* __restrict__ wqb, const float* __restrict__ wkva,
    const float* __restrict__ wkvb, const float* __restrict__ wout,
    u16* __restrict__ xb, u16* __restrict__ wqab, u16* __restrict__ wqbb,
    u16* __restrict__ wkvab, u16* __restrict__ wkvbb, u16* __restrict__ woutb,
    float2* __restrict__ tbl)
{
    if (blockIdx.x < 128) {
        const int idx = blockIdx.x * 256 + threadIdx.x;   // 32768
        const int s = idx >> 4, i = idx & 15;
        const float invf = exp2f(-(float)i * ROPE_L2);
        float sn, c;
        sincosf((float)s * invf, &sn, &c);
        tbl[idx] = make_float2(c, sn);
        return;
    }
    long i = ((long)(blockIdx.x - 128) * 256 + threadIdx.x) * 8;
    const long c0 = N_X, c1 = c0 + N_QA, c2 = c1 + N_QB, c3 = c2 + N_KVA, c4 = c3 + N_KVB;
    const float* src; u16* dst; long off;
    if      (i < c0) { src = x;    dst = xb;    off = i; }
    else if (i < c1) { src = wqa;  dst = wqab;  off = i - c0; }
    else if (i < c2) { src = wqb;  dst = wqbb;  off = i - c1; }
    else if (i < c3) { src = wkva; dst = wkvab; off = i - c2; }
    else if (i < c4) { src = wkvb; dst = wkvbb; off = i - c3; }
    else             { src = wout; dst = woutb; off = i - c4; }
    float v[8];
    *(float4*)v       = *(const float4*)(src + off);
    *(float4*)(v + 4) = *(const float4*)(src + off + 4);
    u32 o[4];
    #pragma unroll
    for (int k = 0; k < 4; ++k)
        o[k] = (u32)f2bf(v[2*k]) | ((u32)f2bf(v[2*k+1]) << 16);
    *(uint4*)(dst + off) = *(const uint4*)o;
}

// ---------------------------------------------------------------------------
// bf16 NT GEMM body, BK=64: C[M,N] = A[M,K] * B[N,K]^T, fp32 accumulate.
// 128x128 tile, 4 waves, single 32KB LDS buffer, one barrier pair per
// 64-wide K-step. Chunk-XOR swizzle key (r&7); inverse swizzle on source.
// ---------------------------------------------------------------------------
template<bool BF16OUT>
__device__ __forceinline__ void gemm_body(
    const u16* __restrict__ A, int lda,
    const u16* __restrict__ Bm, int ldb,
    void* __restrict__ Cout, int ldc, int N, int K,
    int m0, int n0, u16* smA, u16* smB)
{
    const int tid = threadIdx.x;
    const int wave = tid >> 6, lane = tid & 63;
    const int wm = wave >> 1, wn = wave & 1;

    f32x4 acc[4][4] = {};
    const int rA0 = wm * 64 + (lane & 15);
    const int rB0 = wn * 64 + (lane & 15);
    const int cfr = lane >> 4;              // 0..3

    const int srow = wave * 8 + (lane >> 3);
    const int slot = lane & 7;

    for (int k0 = 0; k0 < K; k0 += 64) {
        #pragma unroll
        for (int j = 0; j < 4; ++j) {
            const int r = j * 32 + srow;
            const int boff = j * 4096 + wave * 1024 + (lane << 4);   // bytes
            const int sw = (slot ^ (r & 7)) * 8;
            gload_lds16(A + (size_t)(m0 + r) * lda + k0 + sw, (char*)smA + boff);
            const int nr = min(n0 + r, N - 1);
            gload_lds16(Bm + (size_t)nr * ldb + k0 + sw, (char*)smB + boff);
        }
        __syncthreads();
        #pragma unroll
        for (int hk = 0; hk < 2; ++hk) {
            bf16x8 af[4], bfr[4];
            #pragma unroll
            for (int f = 0; f < 4; ++f) {
                const int rA = rA0 + f * 16;
                af[f]  = *(const bf16x8*)(smA + rA * 64 + (((hk * 4 + cfr) ^ (rA & 7)) * 8));
                const int rB = rB0 + f * 16;
                bfr[f] = *(const bf16x8*)(smB + rB * 64 + (((hk * 4 + cfr) ^ (rB & 7)) * 8));
            }
            #pragma unroll
            for (int i = 0; i < 4; ++i)
                #pragma unroll
                for (int j = 0; j < 4; ++j)
                    acc[i][j] = __builtin_amdgcn_mfma_f32_16x16x32_bf16(af[i], bfr[j], acc[i][j], 0, 0, 0);
        }
        __syncthreads();
    }

    const int cn = lane & 15, rq = lane >> 4;
    #pragma unroll
    for (int i = 0; i < 4; ++i) {
        #pragma unroll
        for (int j = 0; j < 4; ++j) {
            const int n = n0 + wn * 64 + j * 16 + cn;
            if (n < N) {
                #pragma unroll
                for (int r = 0; r < 4; ++r) {
                    const size_t row = (size_t)(m0 + wm * 64 + i * 16 + rq * 4 + r);
                    if (BF16OUT) ((u16*)Cout)[row * ldc + n] = f2bf(acc[i][j][r]);
                    else         ((float*)Cout)[row * ldc + n] = acc[i][j][r];
                }
            }
        }
    }
}

// XCD-chunked block swizzle: keep ~nblk/8 consecutive work items per XCD.
__device__ __forceinline__ int swz_bid() {
    const int nx = gridDim.x;
    const int bid = blockIdx.x + nx * blockIdx.y;
    const int cpx = (nx * gridDim.y) >> 3;     // grid total must be %8==0
    return (bid & 7) * cpx + (bid >> 3);
}

template<bool BF16OUT>
__global__ __launch_bounds__(256) void gemm_bt_bf16(
    const u16* __restrict__ A, int lda,
    const u16* __restrict__ Bm, int ldb,
    void* __restrict__ Cout, int ldc, int N, int K)
{
    __shared__ u16 smA[128 * 64];
    __shared__ u16 smB[128 * 64];
    const int w = swz_bid();
    const int nx = gridDim.x;
    gemm_body<BF16OUT>(A, lda, Bm, ldb, Cout, ldc, N, K,
                       (w / nx) * 128, (w % nx) * 128, smA, smB);
}

// fused gemm1+gemm4: both read A=xb (K=1024). bx<4 -> qc (N=512, fp32),
// else kva (N=544, fp32).
__global__ __launch_bounds__(256) void gemm_dual(
    const u16* __restrict__ A,
    const u16* __restrict__ B1, float* __restrict__ C1,
    const u16* __restrict__ B2, float* __restrict__ C2)
{
    __shared__ u16 smA[128 * 64];
    __shared__ u16 smB[128 * 64];
    const int w = swz_bid();
    const int bx = w % 9, by = w / 9;
    if (bx < 4)
        gemm_body<false>(A, 1024, B1, 1024, C1, 512, 512, 1024,
                         by * 128, bx * 128, smA, smB);
    else
        gemm_body<false>(A, 1024, B2, 1024, C2, 544, 544, 1024,
                         by * 128, (bx - 4) * 128, smA, smB);
}

// ---------------------------------------------------------------------------
// fused LayerNorms (fp32 in): blocks [0,4096) -> LN(qc)->qcb;
// [4096,8192) -> LN(kva)->ckvb + RoPE(kva[:,512:544])->kpe (fp32).
// ---------------------------------------------------------------------------
__global__ __launch_bounds__(256) void ln2_kernel(
    const float* __restrict__ qc, const float* __restrict__ kva,
    const float* __restrict__ g_qa, const float* __restrict__ b_qa,
    const float* __restrict__ g_kva, const float* __restrict__ b_kva,
    u16* __restrict__ qcb, u16* __restrict__ ckvb,
    float* __restrict__ kpe, const float2* __restrict__ tbl)
{
    const bool qpart = blockIdx.x < 4096;
    const int row = blockIdx.x & 4095;
    const float* in    = qpart ? qc : kva;
    const int ld       = qpart ? 512 : 544;
    const float* gamma = qpart ? g_qa : g_kva;
    const float* beta  = qpart ? b_qa : b_kva;
    u16* outb          = qpart ? qcb : ckvb;

    const float* p = in + (size_t)row * ld;
    const int t = threadIdx.x;
    float v0 = p[t], v1 = p[t + 256];

    __shared__ float red[4];
    const int wave = t >> 6, lane = t & 63;

    float s = v0 + v1;
    #pragma unroll
    for (int o = 1; o < 64; o <<= 1) s += __shfl_xor(s, o);
    if (lane == 0) red[wave] = s;
    __syncthreads();
    const float mu = (red[0] + red[1] + red[2] + red[3]) * (1.f / 512.f);

    const float d0 = v0 - mu, d1 = v1 - mu;
    float s2 = d0 * d0 + d1 * d1;
    #pragma unroll
    for (int o = 1; o < 64; o <<= 1) s2 += __shfl_xor(s2, o);
    __syncthreads();
    if (lane == 0) red[wave] = s2;
    __syncthreads();
    const float var = (red[0] + red[1] + red[2] + red[3]) * (1.f / 512.f);
    const float rs = rsqrtf(var + 1e-5f);

    outb[(size_t)row * 512 + t]       = f2bf(d0 * rs * gamma[t]       + beta[t]);
    outb[(size_t)row * 512 + t + 256] = f2bf(d1 * rs * gamma[t + 256] + beta[t + 256]);

    if (!qpart && t < 16) {
        const int spos = row & (S_SZ - 1);
        const float2 cs = tbl[spos * 16 + t];
        const float x1 = p[512 + 2*t], x2 = p[512 + 2*t + 1];
        kpe[(size_t)row * 32 + 2*t]     = x1 * cs.x - x2 * cs.y;
        kpe[(size_t)row * 32 + 2*t + 1] = x1 * cs.y + x2 * cs.x;
    }
}

// ---------------------------------------------------------------------------
// fused q-GEMM + kv-GEMM + k_pe broadcast (grid 21 x 32), BK=64 loop:
//  bx<8  : q = qcb @ Wqb^T; epilogue fuses RoPE + ATT_SCALE + swizzled pack
//          directly into qpack (B*H, S, 64)
//  bx<20 : kv = ckvb @ Wkvb^T; epilogue scatters k_nope into kpack and
//          v (transposed, pi-permuted, swizzled) into vt
//  bx==20: broadcast roped k_pe (fp32 kpe) into kpack for all 16 heads
// ---------------------------------------------------------------------------
__global__ __launch_bounds__(256) void gemm_qkv(
    const u16* __restrict__ qcb, const u16* __restrict__ wqbb,
    const u16* __restrict__ ckvb, const u16* __restrict__ wkvbb,
    const float* __restrict__ kpe, const float2* __restrict__ tbl,
    u16* __restrict__ qpack, u16* __restrict__ kpack, u16* __restrict__ vt)
{
    __shared__ u16 smA[128 * 64];
    __shared__ u16 smB[128 * 64];
    const int tid = threadIdx.x;
    const int wsw = swz_bid();
    const int bx = wsw % 21, by = wsw / 21;

    if (bx == 20) {
        // k_pe broadcast: 128 rows x chunks p=4..7, 16 head copies each
        #pragma unroll
        for (int rr = 0; rr < 2; ++rr) {
            const int row = by * 128 + rr * 64 + (tid >> 2);
            const int p = 4 + (tid & 3);
            const int s = row & (S_SZ - 1), b = row >> 11;
            const float* src = kpe + (size_t)row * 32 + (p - 4) * 8;
            float v[8];
            *(float4*)v       = *(const float4*)(src);
            *(float4*)(v + 4) = *(const float4*)(src + 4);
            u32 o[4];
            #pragma unroll
            for (int k = 0; k < 4; ++k)
                o[k] = (u32)f2bf(v[2*k]) | ((u32)f2bf(v[2*k+1]) << 16);
            const int sch = p ^ (s & 7);
            #pragma unroll
            for (int h = 0; h < 16; ++h)
                *(uint4*)(kpack + (((size_t)(b * 16 + h) * S_SZ + s) * 64) + sch * 8) = *(const uint4*)o;
        }
        return;
    }

    const int wave = tid >> 6, lane = tid & 63;
    const int wm = wave >> 1, wn = wave & 1;
    const bool qpath = bx < 8;
    const u16* A  = qpath ? qcb : ckvb;
    const u16* Bm = qpath ? wqbb : wkvbb;
    const int n0 = (qpath ? bx : bx - 8) * 128;
    const int m0 = by * 128;

    f32x4 acc[4][4] = {};
    const int rA0 = wm * 64 + (lane & 15);
    const int rB0 = wn * 64 + (lane & 15);
    const int cfr = lane >> 4;
    const int srow = wave * 8 + (lane >> 3);
    const int slot = lane & 7;

    for (int k0 = 0; k0 < 512; k0 += 64) {
        #pragma unroll
        for (int j = 0; j < 4; ++j) {
            const int r = j * 32 + srow;
            const int boff = j * 4096 + wave * 1024 + (lane << 4);
            const int sw = (slot ^ (r & 7)) * 8;
            gload_lds16(A + (size_t)(m0 + r) * 512 + k0 + sw, (char*)smA + boff);
            gload_lds16(Bm + (size_t)(n0 + r) * 512 + k0 + sw, (char*)smB + boff);
        }
        __syncthreads();
        #pragma unroll
        for (int hk = 0; hk < 2; ++hk) {
            bf16x8 af[4], bfr[4];
            #pragma unroll
            for (int f = 0; f < 4; ++f) {
                const int rA = rA0 + f * 16;
                af[f]  = *(const bf16x8*)(smA + rA * 64 + (((hk * 4 + cfr) ^ (rA & 7)) * 8));
                const int rB = rB0 + f * 16;
                bfr[f] = *(const bf16x8*)(smB + rB * 64 + (((hk * 4 + cfr) ^ (rB & 7)) * 8));
            }
            #pragma unroll
            for (int i = 0; i < 4; ++i)
                #pragma unroll
                for (int j = 0; j < 4; ++j)
                    acc[i][j] = __builtin_amdgcn_mfma_f32_16x16x32_bf16(af[i], bfr[j], acc[i][j], 0, 0, 0);
        }
        __syncthreads();
    }

    const int cn = lane & 15, rq = lane >> 4;
    if (qpath) {
        #pragma unroll
        for (int i = 0; i < 4; ++i) {
            #pragma unroll
            for (int j = 0; j < 4; ++j) {
                const int n = n0 + wn * 64 + j * 16 + cn;
                const int d = n & 63, h = n >> 6;
                #pragma unroll
                for (int r = 0; r < 4; ++r) {
                    const int row = m0 + wm * 64 + i * 16 + rq * 4 + r;
                    const int s = row & (S_SZ - 1), b = row >> 11;
                    const float val = acc[i][j][r];
                    const float prt = __shfl_xor(val, 1);   // RoPE pair partner
                    float o;
                    if (d >= 32) {
                        const float2 cs = tbl[s * 16 + ((d - 32) >> 1)];
                        o = (d & 1) ? (prt * cs.y + val * cs.x)
                                    : (val * cs.x - prt * cs.y);
                    } else {
                        o = val;
                    }
                    o *= ATT_SCALE;
                    const int sch = (d >> 3) ^ (s & 7);
                    qpack[(((size_t)(b * 16 + h) * S_SZ + s) * 64) + sch * 8 + (d & 7)] = f2bf(o);
                }
            }
        }
    } else {
        // scatter directly into kpack (k_nope) / vt (transposed + pi + swizzle)
        #pragma unroll
        for (int j = 0; j < 4; ++j) {
            const int n = n0 + wn * 64 + j * 16 + cn;   // 0..1535
            const int h = n / 96;
            const int dd = n - h * 96;
            const bool isk = dd < 32;
            const int d = dd - 32;
            #pragma unroll
            for (int i = 0; i < 4; ++i) {
                #pragma unroll
                for (int r = 0; r < 4; ++r) {
                    const int row = m0 + wm * 64 + i * 16 + rq * 4 + r;
                    const int s = row & (S_SZ - 1), b = row >> 11;
                    const u16 val = f2bf(acc[i][j][r]);
                    if (isk) {
                        kpack[(((size_t)(b * 16 + h) * S_SZ + s) * 64)
                              + (((dd >> 3) ^ (s & 7)) * 8) + (dd & 7)] = val;
                    } else {
                        const int kk = s & 63, kt = s >> 6;
                        // jj = pi_v^{-1}(kk): slot whose permuted key is kk
                        const int jj = (kk & 32) | ((kk & 8) << 1) | ((kk & 4) << 1)
                                     | ((kk & 16) >> 2) | (kk & 3);
                        vt[(((size_t)(b * 16 + h) * 32 + kt) * 64 + d) * 64
                           + (((jj >> 3) ^ (d & 7)) * 8) + (jj & 7)] = val;
                    }
                }
            }
        }
    }
}

// ---------------------------------------------------------------------------
// MFMA flash attention, swapped-operand, QBLK=128, no max tracking,
// SPLIT-K in-block: 4 waves; waves 0-1 keys [0,1024), waves 2-3 [1024,2048).
// Each wave owns 64 q-rows (qb=4) -> LDS K/V fragment reads per score are
// HALVED vs the 8-wave/32-row version (the kernel was LDS-read bound).
// Partials additive; kw==1 waves dump acc/l to LDS once, kw==0 combine+store.
// ---------------------------------------------------------------------------
__global__ __launch_bounds__(256, 2) void attn_mfma_kernel(
    const u16* __restrict__ qpack, const u16* __restrict__ kpack,
    const u16* __restrict__ vt, u16* __restrict__ attout)
{
    __shared__ u16 KV[2][2][2][4096];   // [half][buf][K/V][tile] = 64 KB

    const int bid = blockIdx.x;                  // 0..511
    const int w0 = (bid & 7) * 64 + (bid >> 3);  // XCD-contiguous work id
    const int qt = w0 & 15, h = (w0 >> 4) & 15, b = w0 >> 8;
    const int bh = b * H_SZ + h;
    const int tid = threadIdx.x, wave = tid >> 6, lane = tid & 63;
    const int kw = wave >> 1, wv = wave & 1;     // K-half, wave-within-half
    const int g = lane >> 4, q15 = lane & 15;

    const u16* kbase = kpack + (size_t)bh * S_SZ * 64 + (size_t)(kw * 16) * 4096;
    const u16* vbase = vt + (size_t)bh * (S_SZ / 64) * 4096 + (size_t)(kw * 16) * 4096;

    // Q fragments straight from global (pre-swizzled): 4 q-blocks x 16 rows
    bf16x8 qa[4][2];
    {
        const u16* qbase = qpack + ((size_t)bh * S_SZ + qt * 128) * 64;
        #pragma unroll
        for (int qb = 0; qb < 4; ++qb) {
            const int r = wv * 64 + qb * 16 + q15;
            #pragma unroll
            for (int dh = 0; dh < 2; ++dh) {
                const int ch = dh * 4 + g;
                qa[qb][dh] = *(const bf16x8*)(qbase + r * 64 + ((ch ^ (r & 7)) * 8));
            }
        }
    }

    // loop-invariant LDS fragment byte offsets (relative to [half][buf] base)
    int koff[4][2], voff[2][4];
    #pragma unroll
    for (int fk = 0; fk < 4; ++fk) {
        const int kc = fk * 16 + q15;
        #pragma unroll
        for (int dh = 0; dh < 2; ++dh)
            koff[fk][dh] = kc * 128 + (((dh * 4 + g) ^ (kc & 7)) * 16);
    }
    #pragma unroll
    for (int kh = 0; kh < 2; ++kh)
        #pragma unroll
        for (int fd = 0; fd < 4; ++fd) {
            const int d = fd * 16 + q15;
            voff[kh][fd] = 8192 + d * 128 + (((kh * 4 + g) ^ (d & 7)) * 16);
        }

    // stage first tile of this half (2 waves cover 8KB K + 8KB V)
    #pragma unroll
    for (int j = 0; j < 4; ++j) {
        const int boff = j * 2048 + wv * 1024;
        gload_lds16(kbase + boff / 2 + lane * 8, (char*)&KV[kw][0][0][0] + boff);
        gload_lds16(vbase + boff / 2 + lane * 8, (char*)&KV[kw][0][1][0] + boff);
    }
    __syncthreads();

    bf16x8 ones;
    #pragma unroll
    for (int e = 0; e < 8; ++e) ones[e] = (bf16_t)1.0f;

    f32x4 acc[4][4] = {};
    f32x4 acc_l[4] = {};

    #pragma unroll 2
    for (int t = 0; t < 16; ++t) {
        const char* base = (const char*)&KV[kw][t & 1][0][0];
        char* nbase = (char*)&KV[kw][(t + 1) & 1][0][0];

        // prefetch next tile of this half
        if (t != 15) {
            const u16* kn = kbase + (size_t)(t + 1) * 4096;
            const u16* vn = vbase + (size_t)(t + 1) * 4096;
            #pragma unroll
            for (int j = 0; j < 4; ++j) {
                const int boff = j * 2048 + wv * 1024;
                gload_lds16(kn + boff / 2 + lane * 8, nbase + boff);
                gload_lds16(vn + boff / 2 + lane * 8, nbase + 8192 + boff);
            }
        }

        // K fragments (shared across all 4 q-blocks)
        bf16x8 kb[4][2];
        #pragma unroll
        for (int fk = 0; fk < 4; ++fk)
            #pragma unroll
            for (int dh = 0; dh < 2; ++dh)
                kb[fk][dh] = *(const bf16x8*)(base + koff[fk][dh]);

        // QK^T (swapped): sc[qb][fk][r] = S[q15][key = fk*16 + 4g + r]
        f32x4 sc[4][4] = {};
        __builtin_amdgcn_s_setprio(1);
        #pragma unroll
        for (int qb = 0; qb < 4; ++qb)
            #pragma unroll
            for (int fk = 0; fk < 4; ++fk)
                #pragma unroll
                for (int dh = 0; dh < 2; ++dh)
                    sc[qb][fk] = __builtin_amdgcn_mfma_f32_16x16x32_bf16(kb[fk][dh], qa[qb][dh], sc[qb][fk], 0, 0, 0);
        __builtin_amdgcn_s_setprio(0);

        // P = exp2(sc) -- raw v_exp_f32
        #pragma unroll
        for (int qb = 0; qb < 4; ++qb)
            #pragma unroll
            for (int fk = 0; fk < 4; ++fk)
                #pragma unroll
                for (int r = 0; r < 4; ++r)
                    sc[qb][fk][r] = __builtin_amdgcn_exp2f(sc[qb][fk][r]);

        // pack P lane-locally: pa[qb][kh] supplies P[key-slot 8g+e][q]
        bf16x8 pa[4][2];
        #pragma unroll
        for (int qb = 0; qb < 4; ++qb)
            #pragma unroll
            for (int kh = 0; kh < 2; ++kh)
                #pragma unroll
                for (int e = 0; e < 4; ++e) {
                    pa[qb][kh][e]     = (bf16_t)sc[qb][2*kh][e];
                    pa[qb][kh][e + 4] = (bf16_t)sc[qb][2*kh + 1][e];
                }

        // V fragments (shared across q-blocks) + PV and l-sum MFMAs
        bf16x8 vb[2][4];
        #pragma unroll
        for (int kh = 0; kh < 2; ++kh)
            #pragma unroll
            for (int fd = 0; fd < 4; ++fd)
                vb[kh][fd] = *(const bf16x8*)(base + voff[kh][fd]);

        __builtin_amdgcn_s_setprio(1);
        #pragma unroll
        for (int kh = 0; kh < 2; ++kh)
            #pragma unroll
            for (int qb = 0; qb < 4; ++qb) {
                #pragma unroll
                for (int fd = 0; fd < 4; ++fd)
                    acc[qb][fd] = __builtin_amdgcn_mfma_f32_16x16x32_bf16(vb[kh][fd], pa[qb][kh], acc[qb][fd], 0, 0, 0);
                acc_l[qb] = __builtin_amdgcn_mfma_f32_16x16x32_bf16(ones, pa[qb][kh], acc_l[qb], 0, 0, 0);
            }
        __builtin_amdgcn_s_setprio(0);

        __syncthreads();
    }

    // combine halves through LDS (reuses KV; all loads drained by barriers).
    // slot stride 68 floats = 272B (16B-aligned); max use 34.8 KB of 64 KB.
    float* ex = (float*)&KV[0][0][0][0];
    const int slot = (wv * 64 + lane) * 68;
    if (kw == 1) {
        #pragma unroll
        for (int qb = 0; qb < 4; ++qb)
            #pragma unroll
            for (int fd = 0; fd < 4; ++fd)
                *(f32x4*)(ex + slot + (qb * 4 + fd) * 4) = acc[qb][fd];
        #pragma unroll
        for (int qb = 0; qb < 4; ++qb)
            ex[slot + 64 + qb] = acc_l[qb][0];
    }
    __syncthreads();
    if (kw == 0) {
        #pragma unroll
        for (int qb = 0; qb < 4; ++qb) {
            const float l2 = acc_l[qb][0] + ex[slot + 64 + qb];
            const float inv = 1.0f / l2;
            const size_t row = (size_t)(b * S_SZ + qt * 128 + wv * 64 + qb * 16 + q15);
            #pragma unroll
            for (int fd = 0; fd < 4; ++fd) {
                const f32x4 o = acc[qb][fd] + *(const f32x4*)(ex + slot + (qb * 4 + fd) * 4);
                const int d0 = fd * 16 + 4 * g;
                u32 wlo = (u32)f2bf(o[0] * inv) | ((u32)f2bf(o[1] * inv) << 16);
                u32 whi = (u32)f2bf(o[2] * inv) | ((u32)f2bf(o[3] * inv) << 16);
                *(uint2*)(attout + row * 1024 + h * 64 + d0) = make_uint2(wlo, whi);
            }
        }
    }
}

// ---------------------------------------------------------------------------
extern "C" void kernel_launch(void* const* d_in, const int* in_sizes, int n_in,
                              void* d_out, int out_size, void* d_ws, size_t ws_size,
                              hipStream_t stream)
{
    (void)in_sizes; (void)n_in; (void)out_size; (void)ws_size;
    const float* x     = (const float*)d_in[0];
    const float* Wqa   = (const float*)d_in[1];
    const float* g_qa  = (const float*)d_in[2];
    const float* b_qa  = (const float*)d_in[3];
    const float* Wqb   = (const float*)d_in[4];
    const float* Wkva  = (const float*)d_in[5];
    const float* g_kva = (const float*)d_in[6];
    const float* b_kva = (const float*)d_in[7];
    const float* Wkvb  = (const float*)d_in[8];
    const float* Wout  = (const float*)d_in[9];
    float* out = (float*)d_out;

    // workspace (u16 units) with two safe aliases:
    //   qpack aliases xb  (xb dead after gemm_dual; qpack written by gemm_qkv)
    //   attout aliases qc (qc dead after ln2; attout written by attn)
    u16* p = (u16*)d_ws;
    u16* xb     = p;
    u16* qpack  = p;  p += 4194304;                 // 8 MB
    float* qc   = (float*)p;
    u16* attout = p;  p += 4194304;                 // 8 MB (2,097,152 f)
    float* kva  = (float*)p;  p += 4456448;         // 8.9 MB (2,228,224 f)
    u16* qcb    = p;  p += 2097152;                 // 4 MB
    u16* ckvb   = p;  p += 2097152;                 // 4 MB
    u16* kpack  = p;  p += 4194304;                 // 8 MB
    u16* vt     = p;  p += 4194304;                 // 8 MB
    float* kpe  = (float*)p;  p += 262144;          // 512 KB (131,072 f)
    float2* tbl = (float2*)p; p += 131072;          // 256 KB (32,768 float2)
    u16* wqab   = p;  p += 524288;
    u16* wqbb   = p;  p += 524288;
    u16* wkvab  = p;  p += 557056;
    u16* wkvbb  = p;  p += 786432;
    u16* woutb  = p;  p += 1048576;

    dim3 blk(256);

    // 1. RoPE table + bf16 casts (one launch)
    init_kernel<<<3856, blk, 0, stream>>>(x, Wqa, Wqb, Wkva, Wkvb, Wout,
                                          xb, wqab, wqbb, wkvab, wkvbb, woutb, tbl);
    // 2. qc = x @ Wqa^T (fp32) and kva = x @ Wkva^T (fp32)  [BK=64]
    gemm_dual<<<dim3(9, 32), blk, 0, stream>>>(xb, wqab, qc, wkvab, kva);
    // 3. both LayerNorms (fp32 in, bf16 out + fp32 kpe)
    ln2_kernel<<<8192, blk, 0, stream>>>(qc, kva, g_qa, b_qa, g_kva, b_kva,
                                         qcb, ckvb, kpe, tbl);
    // 4. q-GEMM -> qpack, kv-GEMM -> kpack/vt direct, k_pe broadcast [BK=64]
    gemm_qkv<<<dim3(21, 32), blk, 0, stream>>>(qcb, wqbb, ckvb, wkvbb, kpe, tbl,
                                               qpack, kpack, vt);
    // 5. flash attention (QBLK=128, 4-wave split-K, 64 q-rows/wave) -> attout
    attn_mfma_kernel<<<dim3(512), dim3(256), 0, stream>>>(qpack, kpack, vt, attout);
    // 6. out = attout @ Wout^T (fp32 -> d_out)  [BK=64]
    gemm_bt_bf16<false><<<dim3(8, 32), blk, 0, stream>>>(attout, 1024, woutb, 1024, out, 1024, 1024, 1024);
}

// Round 13
// 127.825 us; speedup vs baseline: 1.0674x; 1.0156x over previous
//
#include <hip/hip_runtime.h>
#include <math.h>

#define B_SZ 2
#define S_SZ 2048
#define E_SZ 1024
#define H_SZ 16
#define HD_SZ 64

// (1/sqrt(HD)) * log2(e) -- fold softmax scale and exp->exp2 into Q
#define ATT_SCALE 0.1803368801111306f
// log2(10000)/16
#define ROPE_L2 0.8304820237218407f

typedef unsigned short u16;
typedef unsigned int u32;
typedef __bf16 bf16_t;
typedef bf16_t bf16x8 __attribute__((ext_vector_type(8)));
typedef float f32x4 __attribute__((ext_vector_type(4)));

__device__ __forceinline__ u16 f2bf(float f) {
    bf16_t h = (bf16_t)f;                 // HW RTNE convert
    union { bf16_t h; u16 u; } v; v.h = h;
    return v.u;
}
__device__ __forceinline__ float bf2f(u16 u) {
    union { u32 u; float f; } v; v.u = ((u32)u) << 16; return v.f;
}

__device__ __forceinline__ void gload_lds16(const void* g, void* l) {
    __builtin_amdgcn_global_load_lds(
        (const __attribute__((address_space(1))) unsigned int*)g,
        (__attribute__((address_space(3))) unsigned int*)l, 16, 0, 0);
}

// ---------------------------------------------------------------------------
// init: RoPE cos/sin table (blocks 0..127) + fp32->bf16 casts (blocks 128..)
// ---------------------------------------------------------------------------
#define N_X   4194304L
#define N_QA  524288L
#define N_QB  524288L
#define N_KVA 557056L
#define N_KVB 786432L

__global__ __launch_bounds__(256) void init_kernel(
    const float* __restrict__ x, const float* __restrict__ wqa,
    const float* __restrict__ wqb, const float* __restrict__ wkva,
    const float* __restrict__ wkvb, const float* __restrict__ wout,
    u16* __restrict__ xb, u16* __restrict__ wqab, u16* __restrict__ wqbb,
    u16* __restrict__ wkvab, u16* __restrict__ wkvbb, u16* __restrict__ woutb,
    float2* __restrict__ tbl)
{
    if (blockIdx.x < 128) {
        const int idx = blockIdx.x * 256 + threadIdx.x;   // 32768
        const int s = idx >> 4, i = idx & 15;
        const float invf = exp2f(-(float)i * ROPE_L2);
        float sn, c;
        sincosf((float)s * invf, &sn, &c);
        tbl[idx] = make_float2(c, sn);
        return;
    }
    long i = ((long)(blockIdx.x - 128) * 256 + threadIdx.x) * 8;
    const long c0 = N_X, c1 = c0 + N_QA, c2 = c1 + N_QB, c3 = c2 + N_KVA, c4 = c3 + N_KVB;
    const float* src; u16* dst; long off;
    if      (i < c0) { src = x;    dst = xb;    off = i; }
    else if (i < c1) { src = wqa;  dst = wqab;  off = i - c0; }
    else if (i < c2) { src = wqb;  dst = wqbb;  off = i - c1; }
    else if (i < c3) { src = wkva; dst = wkvab; off = i - c2; }
    else if (i < c4) { src = wkvb; dst = wkvbb; off = i - c3; }
    else             { src = wout; dst = woutb; off = i - c4; }
    float v[8];
    *(float4*)v       = *(const float4*)(src + off);
    *(float4*)(v + 4) = *(const float4*)(src + off + 4);
    u32 o[4];
    #pragma unroll
    for (int k = 0; k < 4; ++k)
        o[k] = (u32)f2bf(v[2*k]) | ((u32)f2bf(v[2*k+1]) << 16);
    *(uint4*)(dst + off) = *(const uint4*)o;
}

// ---------------------------------------------------------------------------
// bf16 NT GEMM body, BK=64: C[M,N] = A[M,K] * B[N,K]^T, fp32 accumulate.
// 128x128 tile, 4 waves, single 32KB LDS buffer, one barrier pair per
// 64-wide K-step. Chunk-XOR swizzle key (r&7); inverse swizzle on source.
// ---------------------------------------------------------------------------
template<bool BF16OUT>
__device__ __forceinline__ void gemm_body(
    const u16* __restrict__ A, int lda,
    const u16* __restrict__ Bm, int ldb,
    void* __restrict__ Cout, int ldc, int N, int K,
    int m0, int n0, u16* smA, u16* smB)
{
    const int tid = threadIdx.x;
    const int wave = tid >> 6, lane = tid & 63;
    const int wm = wave >> 1, wn = wave & 1;

    f32x4 acc[4][4] = {};
    const int rA0 = wm * 64 + (lane & 15);
    const int rB0 = wn * 64 + (lane & 15);
    const int cfr = lane >> 4;              // 0..3

    const int srow = wave * 8 + (lane >> 3);
    const int slot = lane & 7;

    for (int k0 = 0; k0 < K; k0 += 64) {
        #pragma unroll
        for (int j = 0; j < 4; ++j) {
            const int r = j * 32 + srow;
            const int boff = j * 4096 + wave * 1024 + (lane << 4);   // bytes
            const int sw = (slot ^ (r & 7)) * 8;
            gload_lds16(A + (size_t)(m0 + r) * lda + k0 + sw, (char*)smA + boff);
            const int nr = min(n0 + r, N - 1);
            gload_lds16(Bm + (size_t)nr * ldb + k0 + sw, (char*)smB + boff);
        }
        __syncthreads();
        #pragma unroll
        for (int hk = 0; hk < 2; ++hk) {
            bf16x8 af[4], bfr[4];
            #pragma unroll
            for (int f = 0; f < 4; ++f) {
                const int rA = rA0 + f * 16;
                af[f]  = *(const bf16x8*)(smA + rA * 64 + (((hk * 4 + cfr) ^ (rA & 7)) * 8));
                const int rB = rB0 + f * 16;
                bfr[f] = *(const bf16x8*)(smB + rB * 64 + (((hk * 4 + cfr) ^ (rB & 7)) * 8));
            }
            #pragma unroll
            for (int i = 0; i < 4; ++i)
                #pragma unroll
                for (int j = 0; j < 4; ++j)
                    acc[i][j] = __builtin_amdgcn_mfma_f32_16x16x32_bf16(af[i], bfr[j], acc[i][j], 0, 0, 0);
        }
        __syncthreads();
    }

    const int cn = lane & 15, rq = lane >> 4;
    #pragma unroll
    for (int i = 0; i < 4; ++i) {
        #pragma unroll
        for (int j = 0; j < 4; ++j) {
            const int n = n0 + wn * 64 + j * 16 + cn;
            if (n < N) {
                #pragma unroll
                for (int r = 0; r < 4; ++r) {
                    const size_t row = (size_t)(m0 + wm * 64 + i * 16 + rq * 4 + r);
                    if (BF16OUT) ((u16*)Cout)[row * ldc + n] = f2bf(acc[i][j][r]);
                    else         ((float*)Cout)[row * ldc + n] = acc[i][j][r];
                }
            }
        }
    }
}

// XCD-chunked block swizzle: keep ~nblk/8 consecutive work items per XCD.
__device__ __forceinline__ int swz_bid() {
    const int nx = gridDim.x;
    const int bid = blockIdx.x + nx * blockIdx.y;
    const int cpx = (nx * gridDim.y) >> 3;     // grid total must be %8==0
    return (bid & 7) * cpx + (bid >> 3);
}

template<bool BF16OUT>
__global__ __launch_bounds__(256) void gemm_bt_bf16(
    const u16* __restrict__ A, int lda,
    const u16* __restrict__ Bm, int ldb,
    void* __restrict__ Cout, int ldc, int N, int K)
{
    __shared__ u16 smA[128 * 64];
    __shared__ u16 smB[128 * 64];
    const int w = swz_bid();
    const int nx = gridDim.x;
    gemm_body<BF16OUT>(A, lda, Bm, ldb, Cout, ldc, N, K,
                       (w / nx) * 128, (w % nx) * 128, smA, smB);
}

// fused gemm1+gemm4: both read A=xb (K=1024). bx<4 -> qc_b (N=512, bf16),
// else kva_b (N=544, bf16).
__global__ __launch_bounds__(256) void gemm_dual(
    const u16* __restrict__ A,
    const u16* __restrict__ B1, u16* __restrict__ C1,
    const u16* __restrict__ B2, u16* __restrict__ C2)
{
    __shared__ u16 smA[128 * 64];
    __shared__ u16 smB[128 * 64];
    const int w = swz_bid();
    const int bx = w % 9, by = w / 9;
    if (bx < 4)
        gemm_body<true>(A, 1024, B1, 1024, C1, 512, 512, 1024,
                        by * 128, bx * 128, smA, smB);
    else
        gemm_body<true>(A, 1024, B2, 1024, C2, 544, 544, 1024,
                        by * 128, (bx - 4) * 128, smA, smB);
}

// ---------------------------------------------------------------------------
// fused LayerNorms (bf16 in): blocks [0,4096) -> LN(qc_b)->qcb;
// [4096,8192) -> LN(kva_b)->ckvb + RoPE(kva_b[:,512:544])->kpe (fp32).
// Thread t handles elements 2t, 2t+1 (one u32 load).
// ---------------------------------------------------------------------------
__global__ __launch_bounds__(256) void ln2_kernel(
    const u16* __restrict__ qc_b, const u16* __restrict__ kva_b,
    const float* __restrict__ g_qa, const float* __restrict__ b_qa,
    const float* __restrict__ g_kva, const float* __restrict__ b_kva,
    u16* __restrict__ qcb, u16* __restrict__ ckvb,
    float* __restrict__ kpe, const float2* __restrict__ tbl)
{
    const bool qpart = blockIdx.x < 4096;
    const int row = blockIdx.x & 4095;
    const u16* in      = qpart ? qc_b : kva_b;
    const int ld       = qpart ? 512 : 544;
    const float* gamma = qpart ? g_qa : g_kva;
    const float* beta  = qpart ? b_qa : b_kva;
    u16* outb          = qpart ? qcb : ckvb;

    const u16* p = in + (size_t)row * ld;
    const int t = threadIdx.x;
    const u32 w01 = *(const u32*)(p + 2 * t);
    float v0 = bf2f((u16)w01), v1 = bf2f((u16)(w01 >> 16));

    __shared__ float red[4];
    const int wave = t >> 6, lane = t & 63;

    float s = v0 + v1;
    #pragma unroll
    for (int o = 1; o < 64; o <<= 1) s += __shfl_xor(s, o);
    if (lane == 0) red[wave] = s;
    __syncthreads();
    const float mu = (red[0] + red[1] + red[2] + red[3]) * (1.f / 512.f);

    const float d0 = v0 - mu, d1 = v1 - mu;
    float s2 = d0 * d0 + d1 * d1;
    #pragma unroll
    for (int o = 1; o < 64; o <<= 1) s2 += __shfl_xor(s2, o);
    __syncthreads();
    if (lane == 0) red[wave] = s2;
    __syncthreads();
    const float var = (red[0] + red[1] + red[2] + red[3]) * (1.f / 512.f);
    const float rs = rsqrtf(var + 1e-5f);

    const float o0 = d0 * rs * gamma[2*t]     + beta[2*t];
    const float o1 = d1 * rs * gamma[2*t + 1] + beta[2*t + 1];
    *(u32*)(outb + (size_t)row * 512 + 2 * t) =
        (u32)f2bf(o0) | ((u32)f2bf(o1) << 16);

    if (!qpart && t < 16) {
        const int spos = row & (S_SZ - 1);
        const float2 cs = tbl[spos * 16 + t];
        const u32 wpe = *(const u32*)(p + 512 + 2 * t);
        const float x1 = bf2f((u16)wpe), x2 = bf2f((u16)(wpe >> 16));
        kpe[(size_t)row * 32 + 2*t]     = x1 * cs.x - x2 * cs.y;
        kpe[(size_t)row * 32 + 2*t + 1] = x1 * cs.y + x2 * cs.x;
    }
}

// ---------------------------------------------------------------------------
// fused q-GEMM + kv-GEMM + k_pe broadcast (grid 21 x 32), BK=64 loop:
//  bx<8  : q = qcb @ Wqb^T; epilogue fuses RoPE + ATT_SCALE + swizzled pack
//          directly into qpack (B*H, S, 64)
//  bx<20 : kv = ckvb @ Wkvb^T; epilogue scatters k_nope into kpack and
//          v (transposed, pi-permuted, swizzled) into vt
//  bx==20: broadcast roped k_pe (fp32 kpe) into kpack for all 16 heads
// ---------------------------------------------------------------------------
__global__ __launch_bounds__(256) void gemm_qkv(
    const u16* __restrict__ qcb, const u16* __restrict__ wqbb,
    const u16* __restrict__ ckvb, const u16* __restrict__ wkvbb,
    const float* __restrict__ kpe, const float2* __restrict__ tbl,
    u16* __restrict__ qpack, u16* __restrict__ kpack, u16* __restrict__ vt)
{
    __shared__ u16 smA[128 * 64];
    __shared__ u16 smB[128 * 64];
    const int tid = threadIdx.x;
    const int wsw = swz_bid();
    const int bx = wsw % 21, by = wsw / 21;

    if (bx == 20) {
        // k_pe broadcast: 128 rows x chunks p=4..7, 16 head copies each
        #pragma unroll
        for (int rr = 0; rr < 2; ++rr) {
            const int row = by * 128 + rr * 64 + (tid >> 2);
            const int p = 4 + (tid & 3);
            const int s = row & (S_SZ - 1), b = row >> 11;
            const float* src = kpe + (size_t)row * 32 + (p - 4) * 8;
            float v[8];
            *(float4*)v       = *(const float4*)(src);
            *(float4*)(v + 4) = *(const float4*)(src + 4);
            u32 o[4];
            #pragma unroll
            for (int k = 0; k < 4; ++k)
                o[k] = (u32)f2bf(v[2*k]) | ((u32)f2bf(v[2*k+1]) << 16);
            const int sch = p ^ (s & 7);
            #pragma unroll
            for (int h = 0; h < 16; ++h)
                *(uint4*)(kpack + (((size_t)(b * 16 + h) * S_SZ + s) * 64) + sch * 8) = *(const uint4*)o;
        }
        return;
    }

    const int wave = tid >> 6, lane = tid & 63;
    const int wm = wave >> 1, wn = wave & 1;
    const bool qpath = bx < 8;
    const u16* A  = qpath ? qcb : ckvb;
    const u16* Bm = qpath ? wqbb : wkvbb;
    const int n0 = (qpath ? bx : bx - 8) * 128;
    const int m0 = by * 128;

    f32x4 acc[4][4] = {};
    const int rA0 = wm * 64 + (lane & 15);
    const int rB0 = wn * 64 + (lane & 15);
    const int cfr = lane >> 4;
    const int srow = wave * 8 + (lane >> 3);
    const int slot = lane & 7;

    for (int k0 = 0; k0 < 512; k0 += 64) {
        #pragma unroll
        for (int j = 0; j < 4; ++j) {
            const int r = j * 32 + srow;
            const int boff = j * 4096 + wave * 1024 + (lane << 4);
            const int sw = (slot ^ (r & 7)) * 8;
            gload_lds16(A + (size_t)(m0 + r) * 512 + k0 + sw, (char*)smA + boff);
            gload_lds16(Bm + (size_t)(n0 + r) * 512 + k0 + sw, (char*)smB + boff);
        }
        __syncthreads();
        #pragma unroll
        for (int hk = 0; hk < 2; ++hk) {
            bf16x8 af[4], bfr[4];
            #pragma unroll
            for (int f = 0; f < 4; ++f) {
                const int rA = rA0 + f * 16;
                af[f]  = *(const bf16x8*)(smA + rA * 64 + (((hk * 4 + cfr) ^ (rA & 7)) * 8));
                const int rB = rB0 + f * 16;
                bfr[f] = *(const bf16x8*)(smB + rB * 64 + (((hk * 4 + cfr) ^ (rB & 7)) * 8));
            }
            #pragma unroll
            for (int i = 0; i < 4; ++i)
                #pragma unroll
                for (int j = 0; j < 4; ++j)
                    acc[i][j] = __builtin_amdgcn_mfma_f32_16x16x32_bf16(af[i], bfr[j], acc[i][j], 0, 0, 0);
        }
        __syncthreads();
    }

    const int cn = lane & 15, rq = lane >> 4;
    if (qpath) {
        #pragma unroll
        for (int i = 0; i < 4; ++i) {
            #pragma unroll
            for (int j = 0; j < 4; ++j) {
                const int n = n0 + wn * 64 + j * 16 + cn;
                const int d = n & 63, h = n >> 6;
                #pragma unroll
                for (int r = 0; r < 4; ++r) {
                    const int row = m0 + wm * 64 + i * 16 + rq * 4 + r;
                    const int s = row & (S_SZ - 1), b = row >> 11;
                    const float val = acc[i][j][r];
                    const float prt = __shfl_xor(val, 1);   // RoPE pair partner
                    float o;
                    if (d >= 32) {
                        const float2 cs = tbl[s * 16 + ((d - 32) >> 1)];
                        o = (d & 1) ? (prt * cs.y + val * cs.x)
                                    : (val * cs.x - prt * cs.y);
                    } else {
                        o = val;
                    }
                    o *= ATT_SCALE;
                    const int sch = (d >> 3) ^ (s & 7);
                    qpack[(((size_t)(b * 16 + h) * S_SZ + s) * 64) + sch * 8 + (d & 7)] = f2bf(o);
                }
            }
        }
    } else {
        // scatter directly into kpack (k_nope) / vt (transposed + pi + swizzle)
        #pragma unroll
        for (int j = 0; j < 4; ++j) {
            const int n = n0 + wn * 64 + j * 16 + cn;   // 0..1535
            const int h = n / 96;
            const int dd = n - h * 96;
            const bool isk = dd < 32;
            const int d = dd - 32;
            #pragma unroll
            for (int i = 0; i < 4; ++i) {
                #pragma unroll
                for (int r = 0; r < 4; ++r) {
                    const int row = m0 + wm * 64 + i * 16 + rq * 4 + r;
                    const int s = row & (S_SZ - 1), b = row >> 11;
                    const u16 val = f2bf(acc[i][j][r]);
                    if (isk) {
                        kpack[(((size_t)(b * 16 + h) * S_SZ + s) * 64)
                              + (((dd >> 3) ^ (s & 7)) * 8) + (dd & 7)] = val;
                    } else {
                        const int kk = s & 63, kt = s >> 6;
                        // jj = pi_v^{-1}(kk): slot whose permuted key is kk
                        const int jj = (kk & 32) | ((kk & 8) << 1) | ((kk & 4) << 1)
                                     | ((kk & 16) >> 2) | (kk & 3);
                        vt[(((size_t)(b * 16 + h) * 32 + kt) * 64 + d) * 64
                           + (((jj >> 3) ^ (d & 7)) * 8) + (jj & 7)] = val;
                    }
                }
            }
        }
    }
}

// ---------------------------------------------------------------------------
// MFMA flash attention, swapped-operand, QBLK=128, no max tracking,
// SPLIT-K in-block: 4 waves; waves 0-1 keys [0,1024), waves 2-3 [1024,2048).
// Each wave owns 64 q-rows. Partials additive; kw==1 waves dump acc/l to
// LDS once, kw==0 combine+store.
// ---------------------------------------------------------------------------
__global__ __launch_bounds__(256, 2) void attn_mfma_kernel(
    const u16* __restrict__ qpack, const u16* __restrict__ kpack,
    const u16* __restrict__ vt, u16* __restrict__ attout)
{
    __shared__ u16 KV[2][2][2][4096];   // [half][buf][K/V][tile] = 64 KB

    const int bid = blockIdx.x;                  // 0..511
    const int w0 = (bid & 7) * 64 + (bid >> 3);  // XCD-contiguous work id
    const int qt = w0 & 15, h = (w0 >> 4) & 15, b = w0 >> 8;
    const int bh = b * H_SZ + h;
    const int tid = threadIdx.x, wave = tid >> 6, lane = tid & 63;
    const int kw = wave >> 1, wv = wave & 1;     // K-half, wave-within-half
    const int g = lane >> 4, q15 = lane & 15;

    const u16* kbase = kpack + (size_t)bh * S_SZ * 64 + (size_t)(kw * 16) * 4096;
    const u16* vbase = vt + (size_t)bh * (S_SZ / 64) * 4096 + (size_t)(kw * 16) * 4096;

    // Q fragments straight from global (pre-swizzled): 4 q-blocks x 16 rows
    bf16x8 qa[4][2];
    {
        const u16* qbase = qpack + ((size_t)bh * S_SZ + qt * 128) * 64;
        #pragma unroll
        for (int qb = 0; qb < 4; ++qb) {
            const int r = wv * 64 + qb * 16 + q15;
            #pragma unroll
            for (int dh = 0; dh < 2; ++dh) {
                const int ch = dh * 4 + g;
                qa[qb][dh] = *(const bf16x8*)(qbase + r * 64 + ((ch ^ (r & 7)) * 8));
            }
        }
    }

    // loop-invariant LDS fragment byte offsets (relative to [half][buf] base)
    int koff[4][2], voff[2][4];
    #pragma unroll
    for (int fk = 0; fk < 4; ++fk) {
        const int kc = fk * 16 + q15;
        #pragma unroll
        for (int dh = 0; dh < 2; ++dh)
            koff[fk][dh] = kc * 128 + (((dh * 4 + g) ^ (kc & 7)) * 16);
    }
    #pragma unroll
    for (int kh = 0; kh < 2; ++kh)
        #pragma unroll
        for (int fd = 0; fd < 4; ++fd) {
            const int d = fd * 16 + q15;
            voff[kh][fd] = 8192 + d * 128 + (((kh * 4 + g) ^ (d & 7)) * 16);
        }

    // stage first tile of this half (2 waves cover 8KB K + 8KB V)
    #pragma unroll
    for (int j = 0; j < 4; ++j) {
        const int boff = j * 2048 + wv * 1024;
        gload_lds16(kbase + boff / 2 + lane * 8, (char*)&KV[kw][0][0][0] + boff);
        gload_lds16(vbase + boff / 2 + lane * 8, (char*)&KV[kw][0][1][0] + boff);
    }
    __syncthreads();

    bf16x8 ones;
    #pragma unroll
    for (int e = 0; e < 8; ++e) ones[e] = (bf16_t)1.0f;

    f32x4 acc[4][4] = {};
    f32x4 acc_l[4] = {};

    #pragma unroll 2
    for (int t = 0; t < 16; ++t) {
        const char* base = (const char*)&KV[kw][t & 1][0][0];
        char* nbase = (char*)&KV[kw][(t + 1) & 1][0][0];

        // prefetch next tile of this half
        if (t != 15) {
            const u16* kn = kbase + (size_t)(t + 1) * 4096;
            const u16* vn = vbase + (size_t)(t + 1) * 4096;
            #pragma unroll
            for (int j = 0; j < 4; ++j) {
                const int boff = j * 2048 + wv * 1024;
                gload_lds16(kn + boff / 2 + lane * 8, nbase + boff);
                gload_lds16(vn + boff / 2 + lane * 8, nbase + 8192 + boff);
            }
        }

        // K fragments (shared across all 4 q-blocks)
        bf16x8 kb[4][2];
        #pragma unroll
        for (int fk = 0; fk < 4; ++fk)
            #pragma unroll
            for (int dh = 0; dh < 2; ++dh)
                kb[fk][dh] = *(const bf16x8*)(base + koff[fk][dh]);

        // QK^T (swapped): sc[qb][fk][r] = S[q15][key = fk*16 + 4g + r]
        f32x4 sc[4][4] = {};
        __builtin_amdgcn_s_setprio(1);
        #pragma unroll
        for (int qb = 0; qb < 4; ++qb)
            #pragma unroll
            for (int fk = 0; fk < 4; ++fk)
                #pragma unroll
                for (int dh = 0; dh < 2; ++dh)
                    sc[qb][fk] = __builtin_amdgcn_mfma_f32_16x16x32_bf16(kb[fk][dh], qa[qb][dh], sc[qb][fk], 0, 0, 0);
        __builtin_amdgcn_s_setprio(0);

        // P = exp2(sc) -- raw v_exp_f32
        #pragma unroll
        for (int qb = 0; qb < 4; ++qb)
            #pragma unroll
            for (int fk = 0; fk < 4; ++fk)
                #pragma unroll
                for (int r = 0; r < 4; ++r)
                    sc[qb][fk][r] = __builtin_amdgcn_exp2f(sc[qb][fk][r]);

        // pack P lane-locally: pa[qb][kh] supplies P[key-slot 8g+e][q]
        bf16x8 pa[4][2];
        #pragma unroll
        for (int qb = 0; qb < 4; ++qb)
            #pragma unroll
            for (int kh = 0; kh < 2; ++kh)
                #pragma unroll
                for (int e = 0; e < 4; ++e) {
                    pa[qb][kh][e]     = (bf16_t)sc[qb][2*kh][e];
                    pa[qb][kh][e + 4] = (bf16_t)sc[qb][2*kh + 1][e];
                }

        // V fragments (shared across q-blocks) + PV and l-sum MFMAs
        bf16x8 vb[2][4];
        #pragma unroll
        for (int kh = 0; kh < 2; ++kh)
            #pragma unroll
            for (int fd = 0; fd < 4; ++fd)
                vb[kh][fd] = *(const bf16x8*)(base + voff[kh][fd]);

        __builtin_amdgcn_s_setprio(1);
        #pragma unroll
        for (int kh = 0; kh < 2; ++kh)
            #pragma unroll
            for (int qb = 0; qb < 4; ++qb) {
                #pragma unroll
                for (int fd = 0; fd < 4; ++fd)
                    acc[qb][fd] = __builtin_amdgcn_mfma_f32_16x16x32_bf16(vb[kh][fd], pa[qb][kh], acc[qb][fd], 0, 0, 0);
                acc_l[qb] = __builtin_amdgcn_mfma_f32_16x16x32_bf16(ones, pa[qb][kh], acc_l[qb], 0, 0, 0);
            }
        __builtin_amdgcn_s_setprio(0);

        __syncthreads();
    }

    // combine halves through LDS (reuses KV; all loads drained by barriers).
    float* ex = (float*)&KV[0][0][0][0];
    const int slot = (wv * 64 + lane) * 68;
    if (kw == 1) {
        #pragma unroll
        for (int qb = 0; qb < 4; ++qb)
            #pragma unroll
            for (int fd = 0; fd < 4; ++fd)
                *(f32x4*)(ex + slot + (qb * 4 + fd) * 4) = acc[qb][fd];
        #pragma unroll
        for (int qb = 0; qb < 4; ++qb)
            ex[slot + 64 + qb] = acc_l[qb][0];
    }
    __syncthreads();
    if (kw == 0) {
        #pragma unroll
        for (int qb = 0; qb < 4; ++qb) {
            const float l2 = acc_l[qb][0] + ex[slot + 64 + qb];
            const float inv = 1.0f / l2;
            const size_t row = (size_t)(b * S_SZ + qt * 128 + wv * 64 + qb * 16 + q15);
            #pragma unroll
            for (int fd = 0; fd < 4; ++fd) {
                const f32x4 o = acc[qb][fd] + *(const f32x4*)(ex + slot + (qb * 4 + fd) * 4);
                const int d0 = fd * 16 + 4 * g;
                u32 wlo = (u32)f2bf(o[0] * inv) | ((u32)f2bf(o[1] * inv) << 16);
                u32 whi = (u32)f2bf(o[2] * inv) | ((u32)f2bf(o[3] * inv) << 16);
                *(uint2*)(attout + row * 1024 + h * 64 + d0) = make_uint2(wlo, whi);
            }
        }
    }
}

// ---------------------------------------------------------------------------
extern "C" void kernel_launch(void* const* d_in, const int* in_sizes, int n_in,
                              void* d_out, int out_size, void* d_ws, size_t ws_size,
                              hipStream_t stream)
{
    (void)in_sizes; (void)n_in; (void)out_size; (void)ws_size;
    const float* x     = (const float*)d_in[0];
    const float* Wqa   = (const float*)d_in[1];
    const float* g_qa  = (const float*)d_in[2];
    const float* b_qa  = (const float*)d_in[3];
    const float* Wqb   = (const float*)d_in[4];
    const float* Wkva  = (const float*)d_in[5];
    const float* g_kva = (const float*)d_in[6];
    const float* b_kva = (const float*)d_in[7];
    const float* Wkvb  = (const float*)d_in[8];
    const float* Wout  = (const float*)d_in[9];
    float* out = (float*)d_out;

    // flat workspace (u16 units); aliases:
    //   qpack aliases xb  (xb dead after gemm_dual; qpack written by gemm_qkv)
    u16* p = (u16*)d_ws;
    u16* xb     = p;
    u16* qpack  = p;  p += 4194304;                 // 8 MB
    u16* attout = p;  p += 4194304;                 // 8 MB
    u16* qc_b   = p;  p += 2097152;                 // 4 MB
    u16* kva_b  = p;  p += 2228224;                 // 4.25 MB
    u16* qcb    = p;  p += 2097152;                 // 4 MB
    u16* ckvb   = p;  p += 2097152;                 // 4 MB
    u16* kpack  = p;  p += 4194304;                 // 8 MB
    u16* vt     = p;  p += 4194304;                 // 8 MB
    float* kpe  = (float*)p;  p += 262144;          // 512 KB (131,072 f)
    float2* tbl = (float2*)p; p += 131072;          // 256 KB (32,768 float2)
    u16* wqab   = p;  p += 524288;
    u16* wqbb   = p;  p += 524288;
    u16* wkvab  = p;  p += 557056;
    u16* wkvbb  = p;  p += 786432;
    u16* woutb  = p;  p += 1048576;

    dim3 blk(256);

    // 1. RoPE table + bf16 casts (one launch)
    init_kernel<<<3856, blk, 0, stream>>>(x, Wqa, Wqb, Wkva, Wkvb, Wout,
                                          xb, wqab, wqbb, wkvab, wkvbb, woutb, tbl);
    // 2. qc_b = x @ Wqa^T (bf16) and kva_b = x @ Wkva^T (bf16)  [BK=64]
    gemm_dual<<<dim3(9, 32), blk, 0, stream>>>(xb, wqab, qc_b, wkvab, kva_b);
    // 3. both LayerNorms (bf16 in, bf16 out + fp32 kpe)
    ln2_kernel<<<8192, blk, 0, stream>>>(qc_b, kva_b, g_qa, b_qa, g_kva, b_kva,
                                         qcb, ckvb, kpe, tbl);
    // 4. q-GEMM -> qpack, kv-GEMM -> kpack/vt direct, k_pe broadcast [BK=64]
    gemm_qkv<<<dim3(21, 32), blk, 0, stream>>>(qcb, wqbb, ckvb, wkvbb, kpe, tbl,
                                               qpack, kpack, vt);
    // 5. flash attention (QBLK=128, 4-wave split-K, 64 q-rows/wave) -> attout
    attn_mfma_kernel<<<dim3(512), dim3(256), 0, stream>>>(qpack, kpack, vt, attout);
    // 6. out = attout @ Wout^T (fp32 -> d_out)  [BK=64]
    gemm_bt_bf16<false><<<dim3(8, 32), blk, 0, stream>>>(attout, 1024, woutb, 1024, out, 1024, 1024, 1024);
}